// Round 1
// baseline (2829.554 us; speedup 1.0000x reference)
//
#include <hip/hip_runtime.h>

// HomoMusicGNN: 3-layer mean-SAGE GNN + LN + residual + 1024-way head.
// Round 0: correctness-first fp32. All GEMMs on the vector ALU (no fp32 MFMA).
//
// Workspace usage: ~235.7 MB (h, agg, chord_per_occ, CSR structures).

#define kNo 80000
#define kNc 20000
#define kNs 5000
#define kNn 500
#define kNd 50
#define kN  105550
#define kH  256
#define kC  1024
#define kE  605000
#define LN_EPS 1e-5f
#define NBLK 413  // ceil(kN/256)

struct EdgeTab {
  const int* p[10];
  int n[10], so[10], dofs[10], cum[11];
};

// ---------------- edge flatten + in-degree count ----------------
__global__ __launch_bounds__(256) void k_edges(EdgeTab t, int* __restrict__ src_g,
                                               int* __restrict__ dst_g,
                                               int* __restrict__ cnt) {
  int e = blockIdx.x * 256 + threadIdx.x;
  if (e >= kE) return;
  int s = 0;
#pragma unroll
  for (int i = 1; i < 10; ++i) s += (e >= t.cum[i]) ? 1 : 0;
  int j = e - t.cum[s];
  const int* p = t.p[s];
  int src = p[j] + t.so[s];
  int dst = p[t.n[s] + j] + t.dofs[s];
  src_g[e] = src;
  dst_g[e] = dst;
  atomicAdd(&cnt[dst], 1);
}

// ---------------- last-writer-wins scatter-set (chord feats -> occ) ----------
__global__ __launch_bounds__(256) void k_winner(const int* __restrict__ ei,
                                                int* __restrict__ winner) {
  int e = blockIdx.x * 256 + threadIdx.x;
  if (e >= kNo) return;
  atomicMax(&winner[ei[kNo + e]], e);
}

__global__ __launch_bounds__(256) void k_scat(const int* __restrict__ ei,
                                              const int* __restrict__ winner,
                                              const float* __restrict__ xch,
                                              float* __restrict__ cpo) {
  int tid = blockIdx.x * 256 + threadIdx.x;
  if (tid >= kNo * 8) return;
  int e = tid >> 3, q = tid & 7;
  int d = ei[kNo + e];
  if (winner[d] == e) {
    int s = ei[e];
    ((float4*)cpo)[d * 8 + q] = ((const float4*)xch)[s * 8 + q];
  }
}

// ---------------- type-specific input projection -> h ----------------
// h[row][t] = sum_k [A1|A2][row][k] * W[t][k] + bias[t] + emb[t]
__global__ __launch_bounds__(256) void k_proj(
    const float* __restrict__ A1, int K1, const float* __restrict__ A2, int K2,
    const float* __restrict__ W, const float* __restrict__ bias,
    const float* __restrict__ emb, float* __restrict__ hout, int nrows) {
  const int KT = K1 + K2;
  const int KTP = (KT + 15) & ~15;
  __shared__ float As[16][100];  // row stride 100 floats (400B, 16B-aligned)
  const int t = threadIdx.x;
  const int r0 = blockIdx.x * 16;
  for (int idx = t; idx < 16 * KTP; idx += 256) {
    int i = idx / KTP, k = idx - i * KTP;
    float v = 0.f;
    int r = r0 + i;
    if (r < nrows && k < KT)
      v = (k < K1) ? A1[(size_t)r * K1 + k] : A2[(size_t)r * K2 + (k - K1)];
    As[i][k] = v;
  }
  __syncthreads();
  float acc[16];
#pragma unroll
  for (int i = 0; i < 16; ++i) acc[i] = 0.f;
  const float* __restrict__ Wrow = W + (size_t)t * KT;
  for (int kc = 0; kc < KTP; kc += 16) {
    float w[16];
#pragma unroll
    for (int j = 0; j < 16; ++j) {
      int kk = kc + j;
      w[j] = (kk < KT) ? Wrow[kk] : 0.f;
    }
#pragma unroll
    for (int i = 0; i < 16; ++i) {
#pragma unroll
      for (int j = 0; j < 16; ++j) acc[i] = fmaf(As[i][kc + j], w[j], acc[i]);
    }
  }
  const float bb = bias[t] + emb[t];
#pragma unroll
  for (int i = 0; i < 16; ++i) {
    int r = r0 + i;
    if (r < nrows) hout[(size_t)r * kH + t] = acc[i] + bb;
  }
}

// ---------------- CSR build: block-scan of in-degrees ----------------
__global__ __launch_bounds__(256) void k_scan1(const int* __restrict__ cnt,
                                               int* __restrict__ bsum) {
  __shared__ int s[256];
  int b = blockIdx.x, t = threadIdx.x;
  int i = b * 256 + t;
  s[t] = (i < kN) ? cnt[i] : 0;
  __syncthreads();
  for (int off = 128; off; off >>= 1) {
    if (t < off) s[t] += s[t + off];
    __syncthreads();
  }
  if (t == 0) bsum[b] = s[0];
}

__global__ __launch_bounds__(512) void k_scan2(const int* __restrict__ bsum,
                                               int* __restrict__ bscan) {
  __shared__ int s[512];
  int t = threadIdx.x;
  s[t] = (t < NBLK) ? bsum[t] : 0;
  __syncthreads();
  for (int off = 1; off < 512; off <<= 1) {
    int v = (t >= off) ? s[t - off] : 0;
    __syncthreads();
    s[t] += v;
    __syncthreads();
  }
  if (t < NBLK) bscan[t] = s[t];
}

__global__ __launch_bounds__(256) void k_scan3(const int* __restrict__ cnt,
                                               const int* __restrict__ bscan,
                                               int* __restrict__ rowptr,
                                               int* __restrict__ cursor,
                                               float* __restrict__ inv) {
  __shared__ int s[256];
  int b = blockIdx.x, t = threadIdx.x;
  int i = b * 256 + t;
  int v = (i < kN) ? cnt[i] : 0;
  s[t] = v;
  __syncthreads();
  for (int off = 1; off < 256; off <<= 1) {
    int u = (t >= off) ? s[t - off] : 0;
    __syncthreads();
    s[t] += u;
    __syncthreads();
  }
  int incl = s[t];
  int base = (b > 0) ? bscan[b - 1] : 0;
  int excl = base + incl - v;
  if (i < kN) {
    rowptr[i] = excl;
    cursor[i] = excl;
    inv[i] = 1.f / (float)(v > 1 ? v : 1);
    if (i == kN - 1) rowptr[kN] = excl + v;
  }
}

__global__ __launch_bounds__(256) void k_fill(const int* __restrict__ src_g,
                                              const int* __restrict__ dst_g,
                                              int* __restrict__ cursor,
                                              int* __restrict__ csr_src) {
  int e = blockIdx.x * 256 + threadIdx.x;
  if (e >= kE) return;
  int d = dst_g[e];
  int slot = atomicAdd(&cursor[d], 1);
  csr_src[slot] = src_g[e];
}

// ---------------- pull-mode mean aggregation: one wave per node --------------
__global__ __launch_bounds__(256) void k_agg(const float* __restrict__ h,
                                             const int* __restrict__ rowptr,
                                             const int* __restrict__ csr_src,
                                             const float* __restrict__ inv,
                                             float* __restrict__ agg) {
  int wave = threadIdx.x >> 6, lane = threadIdx.x & 63;
  int node = blockIdx.x * 4 + wave;
  if (node >= kN) return;
  int jb = rowptr[node], je = rowptr[node + 1];
  float4 acc = make_float4(0.f, 0.f, 0.f, 0.f);
  for (int j = jb; j < je; ++j) {
    int s = csr_src[j];
    const float4 v = *(const float4*)(h + (size_t)s * kH + lane * 4);
    acc.x += v.x; acc.y += v.y; acc.z += v.z; acc.w += v.w;
  }
  const float ic = inv[node];
  float4 o;
  o.x = acc.x * ic; o.y = acc.y * ic; o.z = acc.z * ic; o.w = acc.w * ic;
  *(float4*)(agg + (size_t)node * kH + lane * 4) = o;
}

// ---------------- fused GEMM (+optional LN + residual) ----------------
// out[i][t] = sum_k A1[i][k]*W1[t][k] (+ A2[i][k]*W2[t][k]) + bias[t]
// USE_LN: LayerNorm over 256 cols, *g + b + resid, write h in place.
// Tile 64 rows x 256 cols per block, 8x8 register tile per thread.
template <bool USE_LN>
__global__ __launch_bounds__(256) void k_gemm(
    const float* __restrict__ A1, const float* __restrict__ W1,
    const float* __restrict__ A2, const float* __restrict__ W2,
    const float* __restrict__ bias, const float* __restrict__ lng,
    const float* __restrict__ lnb, const float* __restrict__ resid,
    float* __restrict__ out, int M, int ostride) {
  __shared__ float As[16][68];   // [k][i], row 272B (16B aligned)
  __shared__ float Ws[16][260];  // [k][t], row 1040B (16B aligned)
  const int tid = threadIdx.x;
  const int c = tid & 31, rg = tid >> 5;
  const int r0 = blockIdx.x * 64;
  const int colbase = blockIdx.y * 256;

  float acc[8][8];
#pragma unroll
  for (int r = 0; r < 8; ++r)
#pragma unroll
    for (int j = 0; j < 8; ++j) acc[r][j] = 0.f;

  const int ai = tid >> 2, akq = tid & 3;

#pragma unroll 1
  for (int ssrc = 0; ssrc < 2; ++ssrc) {
    const float* __restrict__ A = ssrc ? A2 : A1;
    const float* __restrict__ W = ssrc ? W2 : W1;
    if (A == nullptr) break;
    const float* __restrict__ Wrow = W + (size_t)(colbase + tid) * kH;
#pragma unroll 1
    for (int kc = 0; kc < kH; kc += 16) {
      {  // stage A tile (64 rows x 16 k) transposed
        float4 v = make_float4(0.f, 0.f, 0.f, 0.f);
        int r = r0 + ai;
        if (r < M) v = *(const float4*)(A + (size_t)r * kH + kc + akq * 4);
        As[akq * 4 + 0][ai] = v.x;
        As[akq * 4 + 1][ai] = v.y;
        As[akq * 4 + 2][ai] = v.z;
        As[akq * 4 + 3][ai] = v.w;
      }
#pragma unroll
      for (int m = 0; m < 4; ++m) {  // stage W tile (256 cols x 16 k) transposed
        float4 v = *(const float4*)(Wrow + kc + m * 4);
        Ws[m * 4 + 0][tid] = v.x;
        Ws[m * 4 + 1][tid] = v.y;
        Ws[m * 4 + 2][tid] = v.z;
        Ws[m * 4 + 3][tid] = v.w;
      }
      __syncthreads();
#pragma unroll
      for (int k = 0; k < 16; ++k) {
        const float4 a0 = *(const float4*)&As[k][rg * 8];
        const float4 a1 = *(const float4*)&As[k][rg * 8 + 4];
        const float4 w0 = *(const float4*)&Ws[k][c * 4];
        const float4 w1 = *(const float4*)&Ws[k][c * 4 + 128];
        const float a[8] = {a0.x, a0.y, a0.z, a0.w, a1.x, a1.y, a1.z, a1.w};
        const float w[8] = {w0.x, w0.y, w0.z, w0.w, w1.x, w1.y, w1.z, w1.w};
#pragma unroll
        for (int r = 0; r < 8; ++r)
#pragma unroll
          for (int j = 0; j < 8; ++j) acc[r][j] = fmaf(a[r], w[j], acc[r][j]);
      }
      __syncthreads();
    }
  }

  const int b0 = colbase + c * 4, b1 = colbase + c * 4 + 128;
  const float4 bv0 = *(const float4*)(bias + b0);
  const float4 bv1 = *(const float4*)(bias + b1);
  const int ri0 = r0 + rg * 8;

  if (USE_LN) {
    const float4 g0 = *(const float4*)(lng + b0);
    const float4 g1 = *(const float4*)(lng + b1);
    const float4 e0 = *(const float4*)(lnb + b0);
    const float4 e1 = *(const float4*)(lnb + b1);
#pragma unroll
    for (int r = 0; r < 8; ++r) {
      const int ri = ri0 + r;
      float v[8];
      v[0] = acc[r][0] + bv0.x; v[1] = acc[r][1] + bv0.y;
      v[2] = acc[r][2] + bv0.z; v[3] = acc[r][3] + bv0.w;
      v[4] = acc[r][4] + bv1.x; v[5] = acc[r][5] + bv1.y;
      v[6] = acc[r][6] + bv1.z; v[7] = acc[r][7] + bv1.w;
      float s = ((v[0] + v[1]) + (v[2] + v[3])) + ((v[4] + v[5]) + (v[6] + v[7]));
#pragma unroll
      for (int d = 1; d < 32; d <<= 1) s += __shfl_xor(s, d);
      const float mu = s * (1.f / 256.f);
      float q = 0.f;
#pragma unroll
      for (int j = 0; j < 8; ++j) {
        float t = v[j] - mu;
        q = fmaf(t, t, q);
      }
#pragma unroll
      for (int d = 1; d < 32; d <<= 1) q += __shfl_xor(q, d);
      const float rstd = rsqrtf(q * (1.f / 256.f) + LN_EPS);
      if (ri < M) {
        const float4 h0 = *(const float4*)(resid + (size_t)ri * kH + b0);
        const float4 h1 = *(const float4*)(resid + (size_t)ri * kH + b1);
        float4 o0, o1;
        o0.x = (v[0] - mu) * rstd * g0.x + e0.x + h0.x;
        o0.y = (v[1] - mu) * rstd * g0.y + e0.y + h0.y;
        o0.z = (v[2] - mu) * rstd * g0.z + e0.z + h0.z;
        o0.w = (v[3] - mu) * rstd * g0.w + e0.w + h0.w;
        o1.x = (v[4] - mu) * rstd * g1.x + e1.x + h1.x;
        o1.y = (v[5] - mu) * rstd * g1.y + e1.y + h1.y;
        o1.z = (v[6] - mu) * rstd * g1.z + e1.z + h1.z;
        o1.w = (v[7] - mu) * rstd * g1.w + e1.w + h1.w;
        *(float4*)(out + (size_t)ri * ostride + b0) = o0;
        *(float4*)(out + (size_t)ri * ostride + b1) = o1;
      }
    }
  } else {
#pragma unroll
    for (int r = 0; r < 8; ++r) {
      const int ri = ri0 + r;
      if (ri >= M) continue;
      float4 o0, o1;
      o0.x = acc[r][0] + bv0.x; o0.y = acc[r][1] + bv0.y;
      o0.z = acc[r][2] + bv0.z; o0.w = acc[r][3] + bv0.w;
      o1.x = acc[r][4] + bv1.x; o1.y = acc[r][5] + bv1.y;
      o1.z = acc[r][6] + bv1.z; o1.w = acc[r][7] + bv1.w;
      *(float4*)(out + (size_t)ri * ostride + b0) = o0;
      *(float4*)(out + (size_t)ri * ostride + b1) = o1;
    }
  }
}

// ---------------- host launch ----------------
extern "C" void kernel_launch(void* const* d_in, const int* in_sizes, int n_in,
                              void* d_out, int out_size, void* d_ws, size_t ws_size,
                              hipStream_t stream) {
  (void)in_sizes; (void)n_in; (void)out_size; (void)ws_size;
  const float* x_occ    = (const float*)d_in[0];
  const float* x_chord  = (const float*)d_in[1];
  const float* x_sec    = (const float*)d_in[2];
  const float* x_note   = (const float*)d_in[3];
  const float* x_sd     = (const float*)d_in[4];
  const int* ei[10];
  for (int i = 0; i < 10; ++i) ei[i] = (const int*)d_in[5 + i];
  const float* W_occ    = (const float*)d_in[15];
  const float* b_occ    = (const float*)d_in[16];
  const float* W_chord  = (const float*)d_in[17];
  const float* b_chord  = (const float*)d_in[18];
  const float* W_sec    = (const float*)d_in[19];
  const float* b_sec    = (const float*)d_in[20];
  const float* W_note   = (const float*)d_in[21];
  const float* b_note   = (const float*)d_in[22];
  const float* W_sd     = (const float*)d_in[23];
  const float* b_sd     = (const float*)d_in[24];
  const float* type_emb = (const float*)d_in[25];
  const float* Wl       = (const float*)d_in[26];
  const float* bl       = (const float*)d_in[27];
  const float* Wr       = (const float*)d_in[28];
  const float* ln_g     = (const float*)d_in[29];
  const float* ln_b     = (const float*)d_in[30];
  const float* Wc       = (const float*)d_in[31];
  const float* bc       = (const float*)d_in[32];

  float* ws      = (float*)d_ws;
  float* h       = ws;                       // 27,020,800 f
  float* agg     = ws + 27020800u;           // 27,020,800 f
  float* cpo     = ws + 54041600u;           // 2,560,000 f
  int*   winner  = (int*)(ws + 56601600u);   // 80,000 i
  int*   src_g   = (int*)(ws + 56681600u);   // 605,000 i
  int*   dst_g   = (int*)(ws + 57286656u);   // 605,000 i
  int*   csr_src = (int*)(ws + 57891712u);   // 605,000 i
  int*   cnt     = (int*)(ws + 58496768u);   // 105,550 i
  int*   rowptr  = (int*)(ws + 58602368u);   // 105,551 i
  int*   cursor  = (int*)(ws + 58707968u);   // 105,550 i
  float* inv     = ws + 58813568u;           // 105,550 f
  int*   bsum    = (int*)(ws + 58919168u);   // 413 i
  int*   bscan   = (int*)(ws + 58919680u);   // 413 i

  hipMemsetAsync(winner, 0xFF, kNo * 4, stream);
  hipMemsetAsync(cpo, 0, (size_t)kNo * 32 * 4, stream);
  hipMemsetAsync(cnt, 0, kN * 4, stream);

  // chord -> occ feature scatter (numpy last-writer-wins)
  k_winner<<<(kNo + 255) / 256, 256, 0, stream>>>(ei[2], winner);
  k_scat<<<(kNo * 8) / 256, 256, 0, stream>>>(ei[2], winner, x_chord, cpo);

  // type projections -> h
  k_proj<<<(kNo + 15) / 16, 256, 0, stream>>>(x_occ, 64, cpo, 32, W_occ, b_occ,
                                              type_emb + 0 * kH, h, kNo);
  k_proj<<<(kNc + 15) / 16, 256, 0, stream>>>(x_chord, 32, nullptr, 0, W_chord, b_chord,
                                              type_emb + 1 * kH, h + (size_t)kNo * kH, kNc);
  k_proj<<<(kNs + 15) / 16, 256, 0, stream>>>(x_sec, 16, nullptr, 0, W_sec, b_sec,
                                              type_emb + 2 * kH, h + (size_t)100000 * kH, kNs);
  k_proj<<<(kNn + 15) / 16, 256, 0, stream>>>(x_note, 16, nullptr, 0, W_note, b_note,
                                              type_emb + 3 * kH, h + (size_t)105000 * kH, kNn);
  k_proj<<<(kNd + 15) / 16, 256, 0, stream>>>(x_sd, 8, nullptr, 0, W_sd, b_sd,
                                              type_emb + 4 * kH, h + (size_t)105500 * kH, kNd);

  // homogeneous edge list + CSR
  EdgeTab tab;
  const int ns_[10]  = {80000, 80000, 80000, 80000, 80000, 5000, 80000, 80000, 20000, 20000};
  const int sos_[10] = {0, 0, 80000, 0, 100000, 100000, 80000, 105000, 80000, 105500};
  const int dos_[10] = {0, 80000, 0, 100000, 0, 100000, 105000, 80000, 105500, 80000};
  int cum = 0;
  for (int i = 0; i < 10; ++i) {
    tab.p[i] = ei[i]; tab.n[i] = ns_[i]; tab.so[i] = sos_[i]; tab.dofs[i] = dos_[i];
    tab.cum[i] = cum; cum += ns_[i];
  }
  tab.cum[10] = cum;  // 605000

  k_edges<<<(kE + 255) / 256, 256, 0, stream>>>(tab, src_g, dst_g, cnt);
  k_scan1<<<NBLK, 256, 0, stream>>>(cnt, bsum);
  k_scan2<<<1, 512, 0, stream>>>(bsum, bscan);
  k_scan3<<<NBLK, 256, 0, stream>>>(cnt, bscan, rowptr, cursor, inv);
  k_fill<<<(kE + 255) / 256, 256, 0, stream>>>(src_g, dst_g, cursor, csr_src);

  // 3 SAGE layers: mean-aggregate, fused GEMM + LN + residual (h in place)
  for (int l = 0; l < 3; ++l) {
    k_agg<<<(kN + 3) / 4, 256, 0, stream>>>(h, rowptr, csr_src, inv, agg);
    k_gemm<true><<<dim3((kN + 63) / 64, 1), 256, 0, stream>>>(
        agg, Wl + (size_t)l * kH * kH, h, Wr + (size_t)l * kH * kH,
        bl + l * kH, ln_g + l * kH, ln_b + l * kH, h, h, kN, kH);
  }

  // classifier head over occ nodes
  k_gemm<false><<<dim3(kNo / 64, 4), 256, 0, stream>>>(
      h, Wc, nullptr, nullptr, bc, nullptr, nullptr, nullptr,
      (float*)d_out, kNo, kC);
}

// Round 2
// 2136.971 us; speedup vs baseline: 1.3241x; 1.3241x over previous
//
#include <hip/hip_runtime.h>

// HomoMusicGNN: 3-layer mean-SAGE GNN + LN + residual + 1024-way head.
// Round 1: GEMMs moved to bf16 MFMA (16x16x32) with 2-term bf16 split
// (hi+lo) for fp32-equivalent accuracy. h kept ONLY as (hi,lo) bf16 pair.
// m97-style global_load_lds staging with global-side XOR swizzle ->
// conflict-free ds_read_b128 fragment reads.

#define kNo 80000
#define kNc 20000
#define kNs 5000
#define kNn 500
#define kNd 50
#define kN  105550
#define kH  256
#define kC  1024
#define kE  605000
#define LN_EPS 1e-5f
#define NBLK 413  // ceil(kN/256)

typedef unsigned int u32;
typedef unsigned short ush;
typedef __attribute__((ext_vector_type(8))) short short8;
typedef __attribute__((ext_vector_type(4))) float f32x4;

__device__ __forceinline__ float b2f(ush b) {
  u32 u = ((u32)b) << 16;
  float f;
  __builtin_memcpy(&f, &u, 4);
  return f;
}
__device__ __forceinline__ ush f2b(float x) {
  u32 u;
  __builtin_memcpy(&u, &x, 4);
  u32 r = (u + 0x7fffu + ((u >> 16) & 1u)) >> 16;
  return (ush)r;
}

__device__ __forceinline__ void gload16(const void* g, void* l) {
  __builtin_amdgcn_global_load_lds((const __attribute__((address_space(1))) u32*)g,
                                   (__attribute__((address_space(3))) u32*)l, 16, 0, 0);
}

struct EdgeTab {
  const int* p[10];
  int n[10], so[10], dofs[10], cum[11];
};

// ---------------- edge flatten + in-degree count ----------------
__global__ __launch_bounds__(256) void k_edges(EdgeTab t, int* __restrict__ src_g,
                                               int* __restrict__ dst_g,
                                               int* __restrict__ cnt) {
  int e = blockIdx.x * 256 + threadIdx.x;
  if (e >= kE) return;
  int s = 0;
#pragma unroll
  for (int i = 1; i < 10; ++i) s += (e >= t.cum[i]) ? 1 : 0;
  int j = e - t.cum[s];
  const int* p = t.p[s];
  int src = p[j] + t.so[s];
  int dst = p[t.n[s] + j] + t.dofs[s];
  src_g[e] = src;
  dst_g[e] = dst;
  atomicAdd(&cnt[dst], 1);
}

// ---------------- last-writer-wins scatter-set (chord feats -> occ) ----------
__global__ __launch_bounds__(256) void k_winner(const int* __restrict__ ei,
                                                int* __restrict__ winner) {
  int e = blockIdx.x * 256 + threadIdx.x;
  if (e >= kNo) return;
  atomicMax(&winner[ei[kNo + e]], e);
}

__global__ __launch_bounds__(256) void k_scat(const int* __restrict__ ei,
                                              const int* __restrict__ winner,
                                              const float* __restrict__ xch,
                                              float* __restrict__ cpo) {
  int tid = blockIdx.x * 256 + threadIdx.x;
  if (tid >= kNo * 8) return;
  int e = tid >> 3, q = tid & 7;
  int d = ei[kNo + e];
  if (winner[d] == e) {
    int s = ei[e];
    ((float4*)cpo)[d * 8 + q] = ((const float4*)xch)[s * 8 + q];
  }
}

// ---------------- type-specific input projection -> h (hi/lo bf16) ----------
__global__ __launch_bounds__(256) void k_proj(
    const float* __restrict__ A1, int K1, const float* __restrict__ A2, int K2,
    const float* __restrict__ W, const float* __restrict__ bias,
    const float* __restrict__ emb, ush* __restrict__ hhi, ush* __restrict__ hlo,
    int nrows) {
  const int KT = K1 + K2;
  const int KTP = (KT + 15) & ~15;
  __shared__ float As[16][100];
  const int t = threadIdx.x;
  const int r0 = blockIdx.x * 16;
  for (int idx = t; idx < 16 * KTP; idx += 256) {
    int i = idx / KTP, k = idx - i * KTP;
    float v = 0.f;
    int r = r0 + i;
    if (r < nrows && k < KT)
      v = (k < K1) ? A1[(size_t)r * K1 + k] : A2[(size_t)r * K2 + (k - K1)];
    As[i][k] = v;
  }
  __syncthreads();
  float acc[16];
#pragma unroll
  for (int i = 0; i < 16; ++i) acc[i] = 0.f;
  const float* __restrict__ Wrow = W + (size_t)t * KT;
  for (int kc = 0; kc < KTP; kc += 16) {
    float w[16];
#pragma unroll
    for (int j = 0; j < 16; ++j) {
      int kk = kc + j;
      w[j] = (kk < KT) ? Wrow[kk] : 0.f;
    }
#pragma unroll
    for (int i = 0; i < 16; ++i) {
#pragma unroll
      for (int j = 0; j < 16; ++j) acc[i] = fmaf(As[i][kc + j], w[j], acc[i]);
    }
  }
  const float bb = bias[t] + emb[t];
#pragma unroll
  for (int i = 0; i < 16; ++i) {
    int r = r0 + i;
    if (r < nrows) {
      float v = acc[i] + bb;
      ush hi = f2b(v);
      hhi[(size_t)r * kH + t] = hi;
      hlo[(size_t)r * kH + t] = f2b(v - b2f(hi));
    }
  }
}

// ---------------- CSR build ----------------
__global__ __launch_bounds__(256) void k_scan1(const int* __restrict__ cnt,
                                               int* __restrict__ bsum) {
  __shared__ int s[256];
  int b = blockIdx.x, t = threadIdx.x;
  int i = b * 256 + t;
  s[t] = (i < kN) ? cnt[i] : 0;
  __syncthreads();
  for (int off = 128; off; off >>= 1) {
    if (t < off) s[t] += s[t + off];
    __syncthreads();
  }
  if (t == 0) bsum[b] = s[0];
}

__global__ __launch_bounds__(512) void k_scan2(const int* __restrict__ bsum,
                                               int* __restrict__ bscan) {
  __shared__ int s[512];
  int t = threadIdx.x;
  s[t] = (t < NBLK) ? bsum[t] : 0;
  __syncthreads();
  for (int off = 1; off < 512; off <<= 1) {
    int v = (t >= off) ? s[t - off] : 0;
    __syncthreads();
    s[t] += v;
    __syncthreads();
  }
  if (t < NBLK) bscan[t] = s[t];
}

__global__ __launch_bounds__(256) void k_scan3(const int* __restrict__ cnt,
                                               const int* __restrict__ bscan,
                                               int* __restrict__ rowptr,
                                               int* __restrict__ cursor,
                                               float* __restrict__ inv) {
  __shared__ int s[256];
  int b = blockIdx.x, t = threadIdx.x;
  int i = b * 256 + t;
  int v = (i < kN) ? cnt[i] : 0;
  s[t] = v;
  __syncthreads();
  for (int off = 1; off < 256; off <<= 1) {
    int u = (t >= off) ? s[t - off] : 0;
    __syncthreads();
    s[t] += u;
    __syncthreads();
  }
  int incl = s[t];
  int base = (b > 0) ? bscan[b - 1] : 0;
  int excl = base + incl - v;
  if (i < kN) {
    rowptr[i] = excl;
    cursor[i] = excl;
    inv[i] = 1.f / (float)(v > 1 ? v : 1);
    if (i == kN - 1) rowptr[kN] = excl + v;
  }
}

__global__ __launch_bounds__(256) void k_fill(const int* __restrict__ src_g,
                                              const int* __restrict__ dst_g,
                                              int* __restrict__ cursor,
                                              int* __restrict__ csr_src) {
  int e = blockIdx.x * 256 + threadIdx.x;
  if (e >= kE) return;
  int d = dst_g[e];
  int slot = atomicAdd(&cursor[d], 1);
  csr_src[slot] = src_g[e];
}

// ---------------- pull-mode mean aggregation (hi/lo in, hi/lo out) ----------
__global__ __launch_bounds__(256) void k_agg(const ush* __restrict__ hhi,
                                             const ush* __restrict__ hlo,
                                             const int* __restrict__ rowptr,
                                             const int* __restrict__ csr_src,
                                             const float* __restrict__ inv,
                                             ush* __restrict__ ahi,
                                             ush* __restrict__ alo) {
  int wave = threadIdx.x >> 6, lane = threadIdx.x & 63;
  int node = blockIdx.x * 4 + wave;
  if (node >= kN) return;
  int jb = rowptr[node], je = rowptr[node + 1];
  float a0 = 0.f, a1 = 0.f, a2 = 0.f, a3 = 0.f;
  for (int j = jb; j < je; ++j) {
    int s = csr_src[j];
    const ushort4 hv = *(const ushort4*)(hhi + (size_t)s * kH + lane * 4);
    const ushort4 lv = *(const ushort4*)(hlo + (size_t)s * kH + lane * 4);
    a0 += b2f(hv.x) + b2f(lv.x);
    a1 += b2f(hv.y) + b2f(lv.y);
    a2 += b2f(hv.z) + b2f(lv.z);
    a3 += b2f(hv.w) + b2f(lv.w);
  }
  const float ic = inv[node];
  a0 *= ic; a1 *= ic; a2 *= ic; a3 *= ic;
  ushort4 ho, lo4;
  ho.x = f2b(a0); lo4.x = f2b(a0 - b2f(ho.x));
  ho.y = f2b(a1); lo4.y = f2b(a1 - b2f(ho.y));
  ho.z = f2b(a2); lo4.z = f2b(a2 - b2f(ho.z));
  ho.w = f2b(a3); lo4.w = f2b(a3 - b2f(ho.w));
  *(ushort4*)(ahi + (size_t)node * kH + lane * 4) = ho;
  *(ushort4*)(alo + (size_t)node * kH + lane * 4) = lo4;
}

// ---------------- MFMA GEMM: sum_p A[p] @ W[p]^T (+bias) [+LN+resid] --------
// Tile: 64 rows x 256 cols, 4 waves (each wave = 64 rows x 64 cols = 4x4
// frags of 16x16). BK=32 staged via global_load_lds w=16, global-side XOR
// chunk swizzle (chunk' = k8 ^ (row&3)) -> conflict-free ds_read_b128.
struct GArgs {
  const ush* A[6];
  const ush* W[6];
  const float* bias;
  const float* lng;
  const float* lnb;
  const ush* rhi;
  const ush* rlo;
  float* outf;
  ush* ohi;
  ush* olo;
  int M, npass, ostride;
};

template <bool LN>
__global__ __launch_bounds__(256) void k_mg(GArgs g) {
  __shared__ ush At[64 * 32];    // 4 KB
  __shared__ ush Wt[256 * 32];   // 16 KB
  __shared__ float redS[4][64];
  __shared__ float redQ[4][64];

  const int tid = threadIdx.x;
  const int wv = tid >> 6;
  const int l = tid & 63;
  const int fr = l & 15, fk = l >> 4;
  const int fchk8 = (fk ^ (fr & 3)) * 8;  // swizzled 16B-chunk offset (ushorts)
  const int r0 = blockIdx.x * 64;
  const int cb = blockIdx.y << 8;

  f32x4 acc[4][4];
#pragma unroll
  for (int m = 0; m < 4; ++m)
#pragma unroll
    for (int n = 0; n < 4; ++n) acc[m][n] = (f32x4)(0.f);

  const int arow = tid >> 2;
  const int agk8 = (tid & 3) ^ (arow & 3);
  const int arowg = (r0 + arow < g.M) ? (r0 + arow) : (g.M - 1);
  const int wgk8 = (tid & 3) ^ (arow & 3);
  ush* Adst = At + tid * 8;  // LDS dest linear: base + lane*16B
  ush* Wdst = Wt + tid * 8;

#pragma unroll 1
  for (int p = 0; p < g.npass; ++p) {
    const ush* ag = g.A[p] + (size_t)arowg * kH + agk8 * 8;
    const ush* wg = g.W[p] + (size_t)(cb + arow) * kH + wgk8 * 8;
#pragma unroll 1
    for (int kc = 0; kc < kH; kc += 32) {
      __syncthreads();  // all waves done reading previous tile
      gload16(ag + kc, Adst);
#pragma unroll
      for (int it = 0; it < 4; ++it)
        gload16(wg + (size_t)it * 64 * kH + kc, Wdst + it * 2048);
      __syncthreads();  // drains vmcnt: staged data visible
      short8 af[4], wf[4];
#pragma unroll
      for (int m = 0; m < 4; ++m)
        af[m] = *(const short8*)(At + (m * 16 + fr) * 32 + fchk8);
#pragma unroll
      for (int n = 0; n < 4; ++n)
        wf[n] = *(const short8*)(Wt + (wv * 64 + n * 16 + fr) * 32 + fchk8);
#pragma unroll
      for (int m = 0; m < 4; ++m)
#pragma unroll
        for (int n = 0; n < 4; ++n)
          acc[m][n] = __builtin_amdgcn_mfma_f32_16x16x32_bf16(af[m], wf[n],
                                                              acc[m][n], 0, 0, 0);
    }
  }

  // bias (per output col)
  float bn[4];
#pragma unroll
  for (int n = 0; n < 4; ++n) bn[n] = g.bias[cb + wv * 64 + n * 16 + fr];
#pragma unroll
  for (int m = 0; m < 4; ++m)
#pragma unroll
    for (int n = 0; n < 4; ++n)
#pragma unroll
      for (int j = 0; j < 4; ++j) acc[m][n][j] += bn[n];

  if (LN) {
    // per-row partial sums within wave (64 cols), then cross-wave via LDS
#pragma unroll
    for (int m = 0; m < 4; ++m)
#pragma unroll
      for (int j = 0; j < 4; ++j) {
        float s = acc[m][0][j] + acc[m][1][j] + acc[m][2][j] + acc[m][3][j];
        float q = acc[m][0][j] * acc[m][0][j] + acc[m][1][j] * acc[m][1][j] +
                  acc[m][2][j] * acc[m][2][j] + acc[m][3][j] * acc[m][3][j];
#pragma unroll
        for (int d = 1; d < 16; d <<= 1) {
          s += __shfl_xor(s, d);
          q += __shfl_xor(q, d);
        }
        if (fr == 0) {
          redS[wv][m * 16 + fk * 4 + j] = s;
          redQ[wv][m * 16 + fk * 4 + j] = q;
        }
      }
    __syncthreads();
    float gg[4], eb[4];
#pragma unroll
    for (int n = 0; n < 4; ++n) {
      gg[n] = g.lng[wv * 64 + n * 16 + fr];
      eb[n] = g.lnb[wv * 64 + n * 16 + fr];
    }
#pragma unroll
    for (int m = 0; m < 4; ++m)
#pragma unroll
      for (int j = 0; j < 4; ++j) {
        const int rt = m * 16 + fk * 4 + j;
        const float S = redS[0][rt] + redS[1][rt] + redS[2][rt] + redS[3][rt];
        const float Q = redQ[0][rt] + redQ[1][rt] + redQ[2][rt] + redQ[3][rt];
        const float mu = S * (1.f / 256.f);
        float var = Q * (1.f / 256.f) - mu * mu;
        var = var > 0.f ? var : 0.f;
        const float rstd = rsqrtf(var + LN_EPS);
        const int ri = r0 + rt;
        if (ri < g.M) {
          const size_t base = (size_t)ri * kH + wv * 64 + fr;
#pragma unroll
          for (int n = 0; n < 4; ++n) {
            const size_t ix = base + n * 16;
            const float res = b2f(g.rhi[ix]) + b2f(g.rlo[ix]);
            const float y = (acc[m][n][j] - mu) * rstd * gg[n] + eb[n] + res;
            const ush hi = f2b(y);
            g.ohi[ix] = hi;
            g.olo[ix] = f2b(y - b2f(hi));
          }
        }
      }
  } else {
#pragma unroll
    for (int m = 0; m < 4; ++m)
#pragma unroll
      for (int j = 0; j < 4; ++j) {
        const int ri = r0 + m * 16 + fk * 4 + j;
        if (ri < g.M) {
          float* op = g.outf + (size_t)ri * g.ostride + cb + wv * 64 + fr;
#pragma unroll
          for (int n = 0; n < 4; ++n) op[n * 16] = acc[m][n][j];
        }
      }
  }
}

// ---------------- weight hi/lo split ----------------
__global__ __launch_bounds__(256) void k_split(const float* __restrict__ s,
                                               ush* __restrict__ hi,
                                               ush* __restrict__ lo, int n) {
  int i = blockIdx.x * 256 + threadIdx.x;
  if (i >= n) return;
  float v = s[i];
  ush h = f2b(v);
  hi[i] = h;
  lo[i] = f2b(v - b2f(h));
}

// ---------------- host launch ----------------
extern "C" void kernel_launch(void* const* d_in, const int* in_sizes, int n_in,
                              void* d_out, int out_size, void* d_ws, size_t ws_size,
                              hipStream_t stream) {
  (void)in_sizes; (void)n_in; (void)out_size; (void)ws_size;
  const float* x_occ    = (const float*)d_in[0];
  const float* x_chord  = (const float*)d_in[1];
  const float* x_sec    = (const float*)d_in[2];
  const float* x_note   = (const float*)d_in[3];
  const float* x_sd     = (const float*)d_in[4];
  const int* ei[10];
  for (int i = 0; i < 10; ++i) ei[i] = (const int*)d_in[5 + i];
  const float* W_occ    = (const float*)d_in[15];
  const float* b_occ    = (const float*)d_in[16];
  const float* W_chord  = (const float*)d_in[17];
  const float* b_chord  = (const float*)d_in[18];
  const float* W_sec    = (const float*)d_in[19];
  const float* b_sec    = (const float*)d_in[20];
  const float* W_note   = (const float*)d_in[21];
  const float* b_note   = (const float*)d_in[22];
  const float* W_sd     = (const float*)d_in[23];
  const float* b_sd     = (const float*)d_in[24];
  const float* type_emb = (const float*)d_in[25];
  const float* Wl       = (const float*)d_in[26];
  const float* bl       = (const float*)d_in[27];
  const float* Wr       = (const float*)d_in[28];
  const float* ln_g     = (const float*)d_in[29];
  const float* ln_b     = (const float*)d_in[30];
  const float* Wc       = (const float*)d_in[31];
  const float* bc       = (const float*)d_in[32];

  char* base = (char*)d_ws;
  ush* h_hi   = (ush*)(base);                  // 54,041,600 B
  ush* h_lo   = (ush*)(base + 54041600u);
  ush* agg_hi = (ush*)(base + 108083200u);
  ush* agg_lo = (ush*)(base + 162124800u);
  char* wb = base + 216166400u;
  ush* Wl_hi = (ush*)(wb);
  ush* Wl_lo = (ush*)(wb + 393216u);
  ush* Wr_hi = (ush*)(wb + 786432u);
  ush* Wr_lo = (ush*)(wb + 1179648u);
  ush* Wc_hi = (ush*)(wb + 1572864u);
  ush* Wc_lo = (ush*)(wb + 2097152u);
  int* ip = (int*)(wb + 2621440u);
  int* csr_src = ip;
  int* cnt     = ip + 605000;
  int* rowptr  = ip + 710550;
  int* cursor  = ip + 816101;
  float* inv   = (float*)(ip + 921651);
  int* bsum    = ip + 1027201;
  int* bscan   = ip + 1027614;
  // transient aliases inside agg_hi region (all dead before first k_agg):
  float* cpo  = (float*)(base + 108083200u);               // 10,240,000 B
  int* winner = (int*)(base + 118323200u);                 // 320,000 B
  int* src_g  = (int*)(base + 118643200u);                 // 2,420,000 B
  int* dst_g  = (int*)(base + 121063200u);                 // 2,420,000 B

  hipMemsetAsync(winner, 0xFF, kNo * 4, stream);
  hipMemsetAsync(cpo, 0, (size_t)kNo * 32 * 4, stream);
  hipMemsetAsync(cnt, 0, kN * 4, stream);

  // weight splits
  k_split<<<768, 256, 0, stream>>>(Wl, Wl_hi, Wl_lo, 3 * kH * kH);
  k_split<<<768, 256, 0, stream>>>(Wr, Wr_hi, Wr_lo, 3 * kH * kH);
  k_split<<<1024, 256, 0, stream>>>(Wc, Wc_hi, Wc_lo, kC * kH);

  // chord -> occ feature scatter (numpy last-writer-wins)
  k_winner<<<(kNo + 255) / 256, 256, 0, stream>>>(ei[2], winner);
  k_scat<<<(kNo * 8) / 256, 256, 0, stream>>>(ei[2], winner, x_chord, cpo);

  // type projections -> h (hi/lo)
  k_proj<<<(kNo + 15) / 16, 256, 0, stream>>>(x_occ, 64, cpo, 32, W_occ, b_occ,
                                              type_emb + 0 * kH, h_hi, h_lo, kNo);
  k_proj<<<(kNc + 15) / 16, 256, 0, stream>>>(x_chord, 32, nullptr, 0, W_chord, b_chord,
                                              type_emb + 1 * kH,
                                              h_hi + (size_t)kNo * kH,
                                              h_lo + (size_t)kNo * kH, kNc);
  k_proj<<<(kNs + 15) / 16, 256, 0, stream>>>(x_sec, 16, nullptr, 0, W_sec, b_sec,
                                              type_emb + 2 * kH,
                                              h_hi + (size_t)100000 * kH,
                                              h_lo + (size_t)100000 * kH, kNs);
  k_proj<<<(kNn + 15) / 16, 256, 0, stream>>>(x_note, 16, nullptr, 0, W_note, b_note,
                                              type_emb + 3 * kH,
                                              h_hi + (size_t)105000 * kH,
                                              h_lo + (size_t)105000 * kH, kNn);
  k_proj<<<(kNd + 15) / 16, 256, 0, stream>>>(x_sd, 8, nullptr, 0, W_sd, b_sd,
                                              type_emb + 4 * kH,
                                              h_hi + (size_t)105500 * kH,
                                              h_lo + (size_t)105500 * kH, kNd);

  // homogeneous edge list + CSR
  EdgeTab tab;
  const int ns_[10]  = {80000, 80000, 80000, 80000, 80000, 5000, 80000, 80000, 20000, 20000};
  const int sos_[10] = {0, 0, 80000, 0, 100000, 100000, 80000, 105000, 80000, 105500};
  const int dos_[10] = {0, 80000, 0, 100000, 0, 100000, 105000, 80000, 105500, 80000};
  int cum = 0;
  for (int i = 0; i < 10; ++i) {
    tab.p[i] = ei[i]; tab.n[i] = ns_[i]; tab.so[i] = sos_[i]; tab.dofs[i] = dos_[i];
    tab.cum[i] = cum; cum += ns_[i];
  }
  tab.cum[10] = cum;

  k_edges<<<(kE + 255) / 256, 256, 0, stream>>>(tab, src_g, dst_g, cnt);
  k_scan1<<<NBLK, 256, 0, stream>>>(cnt, bsum);
  k_scan2<<<1, 512, 0, stream>>>(bsum, bscan);
  k_scan3<<<NBLK, 256, 0, stream>>>(cnt, bscan, rowptr, cursor, inv);
  k_fill<<<(kE + 255) / 256, 256, 0, stream>>>(src_g, dst_g, cursor, csr_src);

  // 3 SAGE layers
  for (int l = 0; l < 3; ++l) {
    k_agg<<<(kN + 3) / 4, 256, 0, stream>>>(h_hi, h_lo, rowptr, csr_src, inv,
                                            agg_hi, agg_lo);
    GArgs a{};
    const size_t off = (size_t)l * kH * kH;
    a.A[0] = agg_hi; a.A[1] = agg_hi; a.A[2] = agg_lo;
    a.A[3] = h_hi;   a.A[4] = h_hi;   a.A[5] = h_lo;
    a.W[0] = Wl_hi + off; a.W[1] = Wl_lo + off; a.W[2] = Wl_hi + off;
    a.W[3] = Wr_hi + off; a.W[4] = Wr_lo + off; a.W[5] = Wr_hi + off;
    a.bias = bl + l * kH;
    a.lng = ln_g + l * kH;
    a.lnb = ln_b + l * kH;
    a.rhi = h_hi; a.rlo = h_lo;
    a.outf = nullptr; a.ohi = h_hi; a.olo = h_lo;
    a.M = kN; a.npass = 6; a.ostride = kH;
    k_mg<true><<<dim3((kN + 63) / 64, 1), 256, 0, stream>>>(a);
  }

  // classifier head over occ nodes
  GArgs c{};
  c.A[0] = h_hi; c.A[1] = h_hi; c.A[2] = h_lo;
  c.W[0] = Wc_hi; c.W[1] = Wc_lo; c.W[2] = Wc_hi;
  c.bias = bc;
  c.rhi = nullptr; c.rlo = nullptr;
  c.outf = (float*)d_out; c.ohi = nullptr; c.olo = nullptr;
  c.M = kNo; c.npass = 3; c.ostride = kC;
  k_mg<false><<<dim3(kNo / 64, 4), 256, 0, stream>>>(c);
}

// Round 3
// 1544.124 us; speedup vs baseline: 1.8325x; 1.3839x over previous
//
#include <hip/hip_runtime.h>

// HomoMusicGNN: 3-layer mean-SAGE GNN + LN + residual + 1024-way head.
// Round 2: h stored as PACKED u32 (hi bf16 << 16 | lo bf16) -> single 16B/lane
// gather in k_agg with wave-wide index prefetch + 4-deep unroll (MLP).
// GEMM: packed-A staging gives hi+lo frags from one tile -> 6 passes fused
// to 2 (48 MFMA per 2-barrier k-step). W kept as separate hi/lo bf16 tiles.

#define kNo 80000
#define kNc 20000
#define kNs 5000
#define kNn 500
#define kNd 50
#define kN  105550
#define kH  256
#define kC  1024
#define kE  605000
#define LN_EPS 1e-5f
#define NBLK 413  // ceil(kN/256)

typedef unsigned int u32;
typedef unsigned short ush;
typedef __attribute__((ext_vector_type(8))) short short8;
typedef __attribute__((ext_vector_type(4))) float f32x4;

__device__ __forceinline__ float b2f(ush b) {
  u32 u = ((u32)b) << 16;
  float f;
  __builtin_memcpy(&f, &u, 4);
  return f;
}
__device__ __forceinline__ ush f2b(float x) {
  u32 u;
  __builtin_memcpy(&u, &x, 4);
  u32 r = (u + 0x7fffu + ((u >> 16) & 1u)) >> 16;
  return (ush)r;
}
__device__ __forceinline__ float up_hi(u32 u) {
  u32 v = u & 0xffff0000u;
  float f;
  __builtin_memcpy(&f, &v, 4);
  return f;
}
__device__ __forceinline__ float up_lo(u32 u) {
  u32 v = u << 16;
  float f;
  __builtin_memcpy(&f, &v, 4);
  return f;
}
__device__ __forceinline__ float upk(u32 u) { return up_hi(u) + up_lo(u); }
__device__ __forceinline__ u32 pk(float x) {
  ush hi = f2b(x);
  ush lo = f2b(x - b2f(hi));
  return (((u32)hi) << 16) | (u32)lo;
}

union S8u {
  u32 w[4];
  short8 s;
};
// 8 packed cols (a=cols k0..k3, b=k4..k7) -> hi short8 + lo short8
__device__ __forceinline__ void unpk8(uint4 a, uint4 b, short8& hi, short8& lo) {
  S8u h, l;
  h.w[0] = (a.x >> 16) | (a.y & 0xffff0000u);
  h.w[1] = (a.z >> 16) | (a.w & 0xffff0000u);
  h.w[2] = (b.x >> 16) | (b.y & 0xffff0000u);
  h.w[3] = (b.z >> 16) | (b.w & 0xffff0000u);
  l.w[0] = (a.x & 0xffffu) | (a.y << 16);
  l.w[1] = (a.z & 0xffffu) | (a.w << 16);
  l.w[2] = (b.x & 0xffffu) | (b.y << 16);
  l.w[3] = (b.z & 0xffffu) | (b.w << 16);
  hi = h.s;
  lo = l.s;
}

__device__ __forceinline__ void gload16(const void* g, void* l) {
  __builtin_amdgcn_global_load_lds((const __attribute__((address_space(1))) u32*)g,
                                   (__attribute__((address_space(3))) u32*)l, 16, 0, 0);
}

struct EdgeTab {
  const int* p[10];
  int n[10], so[10], dofs[10], cum[11];
};

// ---------------- edge flatten + in-degree count ----------------
__global__ __launch_bounds__(256) void k_edges(EdgeTab t, int* __restrict__ src_g,
                                               int* __restrict__ dst_g,
                                               int* __restrict__ cnt) {
  int e = blockIdx.x * 256 + threadIdx.x;
  if (e >= kE) return;
  int s = 0;
#pragma unroll
  for (int i = 1; i < 10; ++i) s += (e >= t.cum[i]) ? 1 : 0;
  int j = e - t.cum[s];
  const int* p = t.p[s];
  int src = p[j] + t.so[s];
  int dst = p[t.n[s] + j] + t.dofs[s];
  src_g[e] = src;
  dst_g[e] = dst;
  atomicAdd(&cnt[dst], 1);
}

// ---------------- last-writer-wins scatter-set (chord feats -> occ) ----------
__global__ __launch_bounds__(256) void k_winner(const int* __restrict__ ei,
                                                int* __restrict__ winner) {
  int e = blockIdx.x * 256 + threadIdx.x;
  if (e >= kNo) return;
  atomicMax(&winner[ei[kNo + e]], e);
}

__global__ __launch_bounds__(256) void k_scat(const int* __restrict__ ei,
                                              const int* __restrict__ winner,
                                              const float* __restrict__ xch,
                                              float* __restrict__ cpo) {
  int tid = blockIdx.x * 256 + threadIdx.x;
  if (tid >= kNo * 8) return;
  int e = tid >> 3, q = tid & 7;
  int d = ei[kNo + e];
  if (winner[d] == e) {
    int s = ei[e];
    ((float4*)cpo)[d * 8 + q] = ((const float4*)xch)[s * 8 + q];
  }
}

// ---------------- type-specific input projection -> h_pk ----------------
__global__ __launch_bounds__(256) void k_proj(
    const float* __restrict__ A1, int K1, const float* __restrict__ A2, int K2,
    const float* __restrict__ W, const float* __restrict__ bias,
    const float* __restrict__ emb, u32* __restrict__ hpk, int nrows) {
  const int KT = K1 + K2;
  const int KTP = (KT + 15) & ~15;
  __shared__ float As[16][100];
  const int t = threadIdx.x;
  const int r0 = blockIdx.x * 16;
  for (int idx = t; idx < 16 * KTP; idx += 256) {
    int i = idx / KTP, k = idx - i * KTP;
    float v = 0.f;
    int r = r0 + i;
    if (r < nrows && k < KT)
      v = (k < K1) ? A1[(size_t)r * K1 + k] : A2[(size_t)r * K2 + (k - K1)];
    As[i][k] = v;
  }
  __syncthreads();
  float acc[16];
#pragma unroll
  for (int i = 0; i < 16; ++i) acc[i] = 0.f;
  const float* __restrict__ Wrow = W + (size_t)t * KT;
  for (int kc = 0; kc < KTP; kc += 16) {
    float w[16];
#pragma unroll
    for (int j = 0; j < 16; ++j) {
      int kk = kc + j;
      w[j] = (kk < KT) ? Wrow[kk] : 0.f;
    }
#pragma unroll
    for (int i = 0; i < 16; ++i) {
#pragma unroll
      for (int j = 0; j < 16; ++j) acc[i] = fmaf(As[i][kc + j], w[j], acc[i]);
    }
  }
  const float bb = bias[t] + emb[t];
#pragma unroll
  for (int i = 0; i < 16; ++i) {
    int r = r0 + i;
    if (r < nrows) hpk[(size_t)r * kH + t] = pk(acc[i] + bb);
  }
}

// ---------------- CSR build ----------------
__global__ __launch_bounds__(256) void k_scan1(const int* __restrict__ cnt,
                                               int* __restrict__ bsum) {
  __shared__ int s[256];
  int b = blockIdx.x, t = threadIdx.x;
  int i = b * 256 + t;
  s[t] = (i < kN) ? cnt[i] : 0;
  __syncthreads();
  for (int off = 128; off; off >>= 1) {
    if (t < off) s[t] += s[t + off];
    __syncthreads();
  }
  if (t == 0) bsum[b] = s[0];
}

__global__ __launch_bounds__(512) void k_scan2(const int* __restrict__ bsum,
                                               int* __restrict__ bscan) {
  __shared__ int s[512];
  int t = threadIdx.x;
  s[t] = (t < NBLK) ? bsum[t] : 0;
  __syncthreads();
  for (int off = 1; off < 512; off <<= 1) {
    int v = (t >= off) ? s[t - off] : 0;
    __syncthreads();
    s[t] += v;
    __syncthreads();
  }
  if (t < NBLK) bscan[t] = s[t];
}

__global__ __launch_bounds__(256) void k_scan3(const int* __restrict__ cnt,
                                               const int* __restrict__ bscan,
                                               int* __restrict__ rowptr,
                                               int* __restrict__ cursor,
                                               float* __restrict__ inv) {
  __shared__ int s[256];
  int b = blockIdx.x, t = threadIdx.x;
  int i = b * 256 + t;
  int v = (i < kN) ? cnt[i] : 0;
  s[t] = v;
  __syncthreads();
  for (int off = 1; off < 256; off <<= 1) {
    int u = (t >= off) ? s[t - off] : 0;
    __syncthreads();
    s[t] += u;
    __syncthreads();
  }
  int incl = s[t];
  int base = (b > 0) ? bscan[b - 1] : 0;
  int excl = base + incl - v;
  if (i < kN) {
    rowptr[i] = excl;
    cursor[i] = excl;
    inv[i] = 1.f / (float)(v > 1 ? v : 1);
    if (i == kN - 1) rowptr[kN] = excl + v;
  }
}

__global__ __launch_bounds__(256) void k_fill(const int* __restrict__ src_g,
                                              const int* __restrict__ dst_g,
                                              int* __restrict__ cursor,
                                              int* __restrict__ csr_src) {
  int e = blockIdx.x * 256 + threadIdx.x;
  if (e >= kE) return;
  int d = dst_g[e];
  int slot = atomicAdd(&cursor[d], 1);
  csr_src[slot] = src_g[e];
}

// ---------------- pull-mode mean aggregation (packed u32) ----------------
__global__ __launch_bounds__(256) void k_agg(const u32* __restrict__ hpk,
                                             const int* __restrict__ rowptr,
                                             const int* __restrict__ csr_src,
                                             const float* __restrict__ inv,
                                             u32* __restrict__ apk) {
  const int wave = threadIdx.x >> 6, lane = threadIdx.x & 63;
  const int node = blockIdx.x * 4 + wave;
  if (node >= kN) return;
  const int jb = rowptr[node], je = rowptr[node + 1];
  float a0 = 0.f, a1 = 0.f, a2 = 0.f, a3 = 0.f;
  const int coff = lane * 4;  // u32 col offset (16B/lane)

  int j = jb;
  while (j < je) {
    const int batch = min(je - j, 64);
    const int myi = (lane < batch) ? csr_src[j + lane] : 0;
    int t = 0;
    for (; t + 4 <= batch; t += 4) {
      const int s0 = __shfl(myi, t);
      const int s1 = __shfl(myi, t + 1);
      const int s2 = __shfl(myi, t + 2);
      const int s3 = __shfl(myi, t + 3);
      const uint4 v0 = *(const uint4*)(hpk + (size_t)s0 * kH + coff);
      const uint4 v1 = *(const uint4*)(hpk + (size_t)s1 * kH + coff);
      const uint4 v2 = *(const uint4*)(hpk + (size_t)s2 * kH + coff);
      const uint4 v3 = *(const uint4*)(hpk + (size_t)s3 * kH + coff);
      a0 += upk(v0.x) + upk(v1.x) + upk(v2.x) + upk(v3.x);
      a1 += upk(v0.y) + upk(v1.y) + upk(v2.y) + upk(v3.y);
      a2 += upk(v0.z) + upk(v1.z) + upk(v2.z) + upk(v3.z);
      a3 += upk(v0.w) + upk(v1.w) + upk(v2.w) + upk(v3.w);
    }
    for (; t < batch; ++t) {
      const int s0 = __shfl(myi, t);
      const uint4 v0 = *(const uint4*)(hpk + (size_t)s0 * kH + coff);
      a0 += upk(v0.x);
      a1 += upk(v0.y);
      a2 += upk(v0.z);
      a3 += upk(v0.w);
    }
    j += batch;
  }
  const float ic = inv[node];
  uint4 o;
  o.x = pk(a0 * ic);
  o.y = pk(a1 * ic);
  o.z = pk(a2 * ic);
  o.w = pk(a3 * ic);
  *(uint4*)(apk + (size_t)node * kH + coff) = o;
}

// ---------------- MFMA GEMM: packed-A, hi/lo-W, fused 3-term split ----------
// out = sum_p [ Ahi@Whi + Ahi@Wlo + Alo@Whi ](p)  (+bias) [+LN+resid]
// Tile 64 rows x 256 cols, 4 waves, 4x4 frags 16x16x32, BK=32.
// A packed u32: row = 8 x16B chunks, swizzle ch^(row&7).
// W bf16: row = 4 x16B chunks, swizzle ch^(row&3).
struct GArgs {
  const u32* A[2];
  const ush* Wh[2];
  const ush* Wl[2];
  const float* bias;
  const float* lng;
  const float* lnb;
  const u32* rpk;
  float* outf;
  u32* opk;
  int M, npass, ostride;
};

template <bool LN>
__global__ __launch_bounds__(256) void k_mg(GArgs g) {
  __shared__ u32 Apk[64 * 32];   // 8 KB
  __shared__ ush Wht[256 * 32];  // 16 KB
  __shared__ ush Wlt[256 * 32];  // 16 KB
  __shared__ float redS[4][64];
  __shared__ float redQ[4][64];

  const int tid = threadIdx.x;
  const int wv = tid >> 6;
  const int l = tid & 63;
  const int fr = l & 15, fk = l >> 4;
  const int r0 = blockIdx.x * 64;
  const int cb = blockIdx.y << 8;

  // fragment-read swizzled chunk offsets
  const int ac0 = (((fk * 2) ^ (fr & 7)) * 4);      // u32 units
  const int ac1 = (((fk * 2 + 1) ^ (fr & 7)) * 4);  // u32 units
  const int wc8 = ((fk ^ (fr & 3)) * 8);            // ush units

  // staging maps
  const int arow = tid >> 3;            // A rows 0..31 (+32 for slot 2)
  const int ach = tid & 7;
  const int wrow = tid >> 2;            // W rows 0..63 (+i*64)
  const int wch = tid & 3;
  const int ar0g = (r0 + arow < g.M) ? (r0 + arow) : (g.M - 1);
  const int ar1g = (r0 + arow + 32 < g.M) ? (r0 + arow + 32) : (g.M - 1);
  const int aswz = (ach ^ (arow & 7)) * 4;   // u32 units ((arow+32)&7 == arow&7)
  const int wswz = (wch ^ (wrow & 3)) * 8;   // ush units ((wrow+i*64)&3 == wrow&3)

  f32x4 acc[4][4];
#pragma unroll
  for (int m = 0; m < 4; ++m)
#pragma unroll
    for (int n = 0; n < 4; ++n) acc[m][n] = (f32x4)(0.f);

#pragma unroll 1
  for (int p = 0; p < g.npass; ++p) {
    const u32* a0 = g.A[p] + (size_t)ar0g * kH + aswz;
    const u32* a1 = g.A[p] + (size_t)ar1g * kH + aswz;
    const ush* wh = g.Wh[p] + (size_t)(cb + wrow) * kH + wswz;
    const ush* wl = g.Wl[p] + (size_t)(cb + wrow) * kH + wswz;
#pragma unroll 1
    for (int kc = 0; kc < kH; kc += 32) {
      __syncthreads();  // all waves done reading previous tile
      gload16(a0 + kc, Apk + tid * 4);
      gload16(a1 + kc, Apk + (tid + 256) * 4);
#pragma unroll
      for (int i = 0; i < 4; ++i) {
        gload16(wh + (size_t)i * 64 * kH + kc, Wht + (tid + i * 256) * 8);
        gload16(wl + (size_t)i * 64 * kH + kc, Wlt + (tid + i * 256) * 8);
      }
      __syncthreads();  // vmcnt drained: staged data visible

      short8 ah[4], al[4], whf[4], wlf[4];
#pragma unroll
      for (int m = 0; m < 4; ++m) {
        const uint4 x = *(const uint4*)(Apk + (m * 16 + fr) * 32 + ac0);
        const uint4 y = *(const uint4*)(Apk + (m * 16 + fr) * 32 + ac1);
        unpk8(x, y, ah[m], al[m]);
      }
#pragma unroll
      for (int n = 0; n < 4; ++n) {
        whf[n] = *(const short8*)(Wht + (wv * 64 + n * 16 + fr) * 32 + wc8);
        wlf[n] = *(const short8*)(Wlt + (wv * 64 + n * 16 + fr) * 32 + wc8);
      }
#pragma unroll
      for (int m = 0; m < 4; ++m)
#pragma unroll
        for (int n = 0; n < 4; ++n) {
          acc[m][n] = __builtin_amdgcn_mfma_f32_16x16x32_bf16(ah[m], whf[n],
                                                              acc[m][n], 0, 0, 0);
          acc[m][n] = __builtin_amdgcn_mfma_f32_16x16x32_bf16(ah[m], wlf[n],
                                                              acc[m][n], 0, 0, 0);
          acc[m][n] = __builtin_amdgcn_mfma_f32_16x16x32_bf16(al[m], whf[n],
                                                              acc[m][n], 0, 0, 0);
        }
    }
  }

  // bias (per output col)
  float bn[4];
#pragma unroll
  for (int n = 0; n < 4; ++n) bn[n] = g.bias[cb + wv * 64 + n * 16 + fr];
#pragma unroll
  for (int m = 0; m < 4; ++m)
#pragma unroll
    for (int n = 0; n < 4; ++n)
#pragma unroll
      for (int j = 0; j < 4; ++j) acc[m][n][j] += bn[n];

  if (LN) {
#pragma unroll
    for (int m = 0; m < 4; ++m)
#pragma unroll
      for (int j = 0; j < 4; ++j) {
        float s = acc[m][0][j] + acc[m][1][j] + acc[m][2][j] + acc[m][3][j];
        float q = acc[m][0][j] * acc[m][0][j] + acc[m][1][j] * acc[m][1][j] +
                  acc[m][2][j] * acc[m][2][j] + acc[m][3][j] * acc[m][3][j];
#pragma unroll
        for (int d = 1; d < 16; d <<= 1) {
          s += __shfl_xor(s, d);
          q += __shfl_xor(q, d);
        }
        if (fr == 0) {
          redS[wv][m * 16 + fk * 4 + j] = s;
          redQ[wv][m * 16 + fk * 4 + j] = q;
        }
      }
    __syncthreads();
    float gg[4], eb[4];
#pragma unroll
    for (int n = 0; n < 4; ++n) {
      gg[n] = g.lng[wv * 64 + n * 16 + fr];
      eb[n] = g.lnb[wv * 64 + n * 16 + fr];
    }
#pragma unroll
    for (int m = 0; m < 4; ++m)
#pragma unroll
      for (int j = 0; j < 4; ++j) {
        const int rt = m * 16 + fk * 4 + j;
        const float S = redS[0][rt] + redS[1][rt] + redS[2][rt] + redS[3][rt];
        const float Q = redQ[0][rt] + redQ[1][rt] + redQ[2][rt] + redQ[3][rt];
        const float mu = S * (1.f / 256.f);
        float var = Q * (1.f / 256.f) - mu * mu;
        var = var > 0.f ? var : 0.f;
        const float rstd = rsqrtf(var + LN_EPS);
        const int ri = r0 + rt;
        if (ri < g.M) {
          const size_t base = (size_t)ri * kH + wv * 64 + fr;
#pragma unroll
          for (int n = 0; n < 4; ++n) {
            const size_t ix = base + n * 16;
            const float res = upk(g.rpk[ix]);
            const float y = (acc[m][n][j] - mu) * rstd * gg[n] + eb[n] + res;
            g.opk[ix] = pk(y);
          }
        }
      }
  } else {
#pragma unroll
    for (int m = 0; m < 4; ++m)
#pragma unroll
      for (int j = 0; j < 4; ++j) {
        const int ri = r0 + m * 16 + fk * 4 + j;
        if (ri < g.M) {
          float* op = g.outf + (size_t)ri * g.ostride + cb + wv * 64 + fr;
#pragma unroll
          for (int n = 0; n < 4; ++n) op[n * 16] = acc[m][n][j];
        }
      }
  }
}

// ---------------- weight hi/lo split ----------------
__global__ __launch_bounds__(256) void k_split(const float* __restrict__ s,
                                               ush* __restrict__ hi,
                                               ush* __restrict__ lo, int n) {
  int i = blockIdx.x * 256 + threadIdx.x;
  if (i >= n) return;
  float v = s[i];
  ush h = f2b(v);
  hi[i] = h;
  lo[i] = f2b(v - b2f(h));
}

// ---------------- host launch ----------------
extern "C" void kernel_launch(void* const* d_in, const int* in_sizes, int n_in,
                              void* d_out, int out_size, void* d_ws, size_t ws_size,
                              hipStream_t stream) {
  (void)in_sizes; (void)n_in; (void)out_size; (void)ws_size;
  const float* x_occ    = (const float*)d_in[0];
  const float* x_chord  = (const float*)d_in[1];
  const float* x_sec    = (const float*)d_in[2];
  const float* x_note   = (const float*)d_in[3];
  const float* x_sd     = (const float*)d_in[4];
  const int* ei[10];
  for (int i = 0; i < 10; ++i) ei[i] = (const int*)d_in[5 + i];
  const float* W_occ    = (const float*)d_in[15];
  const float* b_occ    = (const float*)d_in[16];
  const float* W_chord  = (const float*)d_in[17];
  const float* b_chord  = (const float*)d_in[18];
  const float* W_sec    = (const float*)d_in[19];
  const float* b_sec    = (const float*)d_in[20];
  const float* W_note   = (const float*)d_in[21];
  const float* b_note   = (const float*)d_in[22];
  const float* W_sd     = (const float*)d_in[23];
  const float* b_sd     = (const float*)d_in[24];
  const float* type_emb = (const float*)d_in[25];
  const float* Wl       = (const float*)d_in[26];
  const float* bl       = (const float*)d_in[27];
  const float* Wr       = (const float*)d_in[28];
  const float* ln_g     = (const float*)d_in[29];
  const float* ln_b     = (const float*)d_in[30];
  const float* Wc       = (const float*)d_in[31];
  const float* bc       = (const float*)d_in[32];

  char* base = (char*)d_ws;
  u32* h_pk   = (u32*)(base);                  // 108,083,200 B
  u32* agg_pk = (u32*)(base + 108083200u);     // 108,083,200 B
  char* wb = base + 216166400u;
  ush* Wl_hi = (ush*)(wb);                     // 393,216 B each
  ush* Wl_lo = (ush*)(wb + 393216u);
  ush* Wr_hi = (ush*)(wb + 786432u);
  ush* Wr_lo = (ush*)(wb + 1179648u);
  ush* Wc_hi = (ush*)(wb + 1572864u);          // 524,288 B each
  ush* Wc_lo = (ush*)(wb + 2097152u);
  int* ip = (int*)(wb + 2621440u);
  int* csr_src = ip;
  int* cnt     = ip + 605000;
  int* rowptr  = ip + 710550;
  int* cursor  = ip + 816101;
  float* inv   = (float*)(ip + 921651);
  int* bsum    = ip + 1027201;
  int* bscan   = ip + 1027614;
  // transient aliases inside agg_pk region (all dead before first k_agg):
  float* cpo  = (float*)(base + 108083200u);   // 10,240,000 B
  int* winner = (int*)(base + 118323200u);     // 320,000 B
  int* src_g  = (int*)(base + 118643200u);     // 2,420,000 B
  int* dst_g  = (int*)(base + 121063200u);     // 2,420,000 B

  hipMemsetAsync(winner, 0xFF, kNo * 4, stream);
  hipMemsetAsync(cpo, 0, (size_t)kNo * 32 * 4, stream);
  hipMemsetAsync(cnt, 0, kN * 4, stream);

  // weight splits
  k_split<<<768, 256, 0, stream>>>(Wl, Wl_hi, Wl_lo, 3 * kH * kH);
  k_split<<<768, 256, 0, stream>>>(Wr, Wr_hi, Wr_lo, 3 * kH * kH);
  k_split<<<1024, 256, 0, stream>>>(Wc, Wc_hi, Wc_lo, kC * kH);

  // chord -> occ feature scatter (numpy last-writer-wins)
  k_winner<<<(kNo + 255) / 256, 256, 0, stream>>>(ei[2], winner);
  k_scat<<<(kNo * 8) / 256, 256, 0, stream>>>(ei[2], winner, x_chord, cpo);

  // type projections -> h_pk
  k_proj<<<(kNo + 15) / 16, 256, 0, stream>>>(x_occ, 64, cpo, 32, W_occ, b_occ,
                                              type_emb + 0 * kH, h_pk, kNo);
  k_proj<<<(kNc + 15) / 16, 256, 0, stream>>>(x_chord, 32, nullptr, 0, W_chord, b_chord,
                                              type_emb + 1 * kH,
                                              h_pk + (size_t)kNo * kH, kNc);
  k_proj<<<(kNs + 15) / 16, 256, 0, stream>>>(x_sec, 16, nullptr, 0, W_sec, b_sec,
                                              type_emb + 2 * kH,
                                              h_pk + (size_t)100000 * kH, kNs);
  k_proj<<<(kNn + 15) / 16, 256, 0, stream>>>(x_note, 16, nullptr, 0, W_note, b_note,
                                              type_emb + 3 * kH,
                                              h_pk + (size_t)105000 * kH, kNn);
  k_proj<<<(kNd + 15) / 16, 256, 0, stream>>>(x_sd, 8, nullptr, 0, W_sd, b_sd,
                                              type_emb + 4 * kH,
                                              h_pk + (size_t)105500 * kH, kNd);

  // homogeneous edge list + CSR
  EdgeTab tab;
  const int ns_[10]  = {80000, 80000, 80000, 80000, 80000, 5000, 80000, 80000, 20000, 20000};
  const int sos_[10] = {0, 0, 80000, 0, 100000, 100000, 80000, 105000, 80000, 105500};
  const int dos_[10] = {0, 80000, 0, 100000, 0, 100000, 105000, 80000, 105500, 80000};
  int cum = 0;
  for (int i = 0; i < 10; ++i) {
    tab.p[i] = ei[i]; tab.n[i] = ns_[i]; tab.so[i] = sos_[i]; tab.dofs[i] = dos_[i];
    tab.cum[i] = cum; cum += ns_[i];
  }
  tab.cum[10] = cum;

  k_edges<<<(kE + 255) / 256, 256, 0, stream>>>(tab, src_g, dst_g, cnt);
  k_scan1<<<NBLK, 256, 0, stream>>>(cnt, bsum);
  k_scan2<<<1, 512, 0, stream>>>(bsum, bscan);
  k_scan3<<<NBLK, 256, 0, stream>>>(cnt, bscan, rowptr, cursor, inv);
  k_fill<<<(kE + 255) / 256, 256, 0, stream>>>(src_g, dst_g, cursor, csr_src);

  // 3 SAGE layers
  for (int l = 0; l < 3; ++l) {
    k_agg<<<(kN + 3) / 4, 256, 0, stream>>>(h_pk, rowptr, csr_src, inv, agg_pk);
    GArgs a{};
    const size_t off = (size_t)l * kH * kH;
    a.A[0] = agg_pk;      a.A[1] = h_pk;
    a.Wh[0] = Wl_hi + off; a.Wh[1] = Wr_hi + off;
    a.Wl[0] = Wl_lo + off; a.Wl[1] = Wr_lo + off;
    a.bias = bl + l * kH;
    a.lng = ln_g + l * kH;
    a.lnb = ln_b + l * kH;
    a.rpk = h_pk;
    a.outf = nullptr;
    a.opk = h_pk;
    a.M = kN; a.npass = 2; a.ostride = kH;
    k_mg<true><<<dim3((kN + 63) / 64, 1), 256, 0, stream>>>(a);
  }

  // classifier head over occ nodes
  GArgs c{};
  c.A[0] = h_pk;
  c.Wh[0] = Wc_hi;
  c.Wl[0] = Wc_lo;
  c.bias = bc;
  c.rpk = nullptr;
  c.outf = (float*)d_out;
  c.opk = nullptr;
  c.M = kNo; c.npass = 1; c.ostride = kC;
  k_mg<false><<<dim3(kNo / 64, 4), 256, 0, stream>>>(c);
}

// Round 4
// 1311.289 us; speedup vs baseline: 2.1578x; 1.1776x over previous
//
#include <hip/hip_runtime.h>

// HomoMusicGNN: 3-layer mean-SAGE GNN + LN + residual + 1024-way head.
// Round 3: input projections moved to MFMA (k_pmg) via packed hi/lo inputs
// (Kp padded to mult of 32) + split/padded weights. Removes the 305 us fp32
// k_proj. k_agg / k_mg unchanged from R2 (validated).

#define kNo 80000
#define kNc 20000
#define kNs 5000
#define kNn 500
#define kNd 50
#define kN  105550
#define kH  256
#define kC  1024
#define kE  605000
#define LN_EPS 1e-5f
#define NBLK 413  // ceil(kN/256)

typedef unsigned int u32;
typedef unsigned short ush;
typedef __attribute__((ext_vector_type(8))) short short8;
typedef __attribute__((ext_vector_type(4))) float f32x4;

__device__ __forceinline__ float b2f(ush b) {
  u32 u = ((u32)b) << 16;
  float f;
  __builtin_memcpy(&f, &u, 4);
  return f;
}
__device__ __forceinline__ ush f2b(float x) {
  u32 u;
  __builtin_memcpy(&u, &x, 4);
  u32 r = (u + 0x7fffu + ((u >> 16) & 1u)) >> 16;
  return (ush)r;
}
__device__ __forceinline__ float up_hi(u32 u) {
  u32 v = u & 0xffff0000u;
  float f;
  __builtin_memcpy(&f, &v, 4);
  return f;
}
__device__ __forceinline__ float up_lo(u32 u) {
  u32 v = u << 16;
  float f;
  __builtin_memcpy(&f, &v, 4);
  return f;
}
__device__ __forceinline__ float upk(u32 u) { return up_hi(u) + up_lo(u); }
__device__ __forceinline__ u32 pk(float x) {
  ush hi = f2b(x);
  ush lo = f2b(x - b2f(hi));
  return (((u32)hi) << 16) | (u32)lo;
}

union S8u {
  u32 w[4];
  short8 s;
};
// 8 packed cols (a=cols k0..k3, b=k4..k7) -> hi short8 + lo short8
__device__ __forceinline__ void unpk8(uint4 a, uint4 b, short8& hi, short8& lo) {
  S8u h, l;
  h.w[0] = (a.x >> 16) | (a.y & 0xffff0000u);
  h.w[1] = (a.z >> 16) | (a.w & 0xffff0000u);
  h.w[2] = (b.x >> 16) | (b.y & 0xffff0000u);
  h.w[3] = (b.z >> 16) | (b.w & 0xffff0000u);
  l.w[0] = (a.x & 0xffffu) | (a.y << 16);
  l.w[1] = (a.z & 0xffffu) | (a.w << 16);
  l.w[2] = (b.x & 0xffffu) | (b.y << 16);
  l.w[3] = (b.z & 0xffffu) | (b.w << 16);
  hi = h.s;
  lo = l.s;
}

__device__ __forceinline__ void gload16(const void* g, void* l) {
  __builtin_amdgcn_global_load_lds((const __attribute__((address_space(1))) u32*)g,
                                   (__attribute__((address_space(3))) u32*)l, 16, 0, 0);
}

struct EdgeTab {
  const int* p[10];
  int n[10], so[10], dofs[10], cum[11];
};

// ---------------- edge flatten + in-degree count ----------------
__global__ __launch_bounds__(256) void k_edges(EdgeTab t, int* __restrict__ src_g,
                                               int* __restrict__ dst_g,
                                               int* __restrict__ cnt) {
  int e = blockIdx.x * 256 + threadIdx.x;
  if (e >= kE) return;
  int s = 0;
#pragma unroll
  for (int i = 1; i < 10; ++i) s += (e >= t.cum[i]) ? 1 : 0;
  int j = e - t.cum[s];
  const int* p = t.p[s];
  int src = p[j] + t.so[s];
  int dst = p[t.n[s] + j] + t.dofs[s];
  src_g[e] = src;
  dst_g[e] = dst;
  atomicAdd(&cnt[dst], 1);
}

// ---------------- last-writer-wins scatter-set (chord feats -> occ) ----------
__global__ __launch_bounds__(256) void k_winner(const int* __restrict__ ei,
                                                int* __restrict__ winner) {
  int e = blockIdx.x * 256 + threadIdx.x;
  if (e >= kNo) return;
  atomicMax(&winner[ei[kNo + e]], e);
}

__global__ __launch_bounds__(256) void k_scat(const int* __restrict__ ei,
                                              const int* __restrict__ winner,
                                              const float* __restrict__ xch,
                                              float* __restrict__ cpo) {
  int tid = blockIdx.x * 256 + threadIdx.x;
  if (tid >= kNo * 8) return;
  int e = tid >> 3, q = tid & 7;
  int d = ei[kNo + e];
  if (winner[d] == e) {
    int s = ei[e];
    ((float4*)cpo)[d * 8 + q] = ((const float4*)xch)[s * 8 + q];
  }
}

// ---------------- input pack: [M][Kp] u32 (hi<<16|lo), zero-padded ----------
__global__ __launch_bounds__(256) void k_pack2(const float* __restrict__ A1, int K1,
                                               const float* __restrict__ A2, int K2,
                                               int Kp, u32* __restrict__ Xp, int M) {
  int tid = blockIdx.x * 256 + threadIdx.x;
  if (tid >= M * Kp) return;
  int r = tid / Kp, c = tid - r * Kp;
  float v = 0.f;
  if (c < K1) v = A1[(size_t)r * K1 + c];
  else if (c < K1 + K2) v = A2[(size_t)r * K2 + (c - K1)];
  Xp[tid] = pk(v);
}

// ---------------- weight split + pad: [256][Kp] hi/lo bf16 ----------------
__global__ __launch_bounds__(256) void k_wsplit(const float* __restrict__ W, int K,
                                                int Kp, ush* __restrict__ hi,
                                                ush* __restrict__ lo) {
  int tid = blockIdx.x * 256 + threadIdx.x;
  if (tid >= 256 * Kp) return;
  int r = tid / Kp, c = tid - r * Kp;
  float v = (c < K) ? W[(size_t)r * K + c] : 0.f;
  ush h = f2b(v);
  hi[tid] = h;
  lo[tid] = f2b(v - b2f(h));
}

// ---------------- MFMA projection: Xp(packed) @ W^T + bias + emb -> h_pk ----
// Tile 64 rows x 256 cols, 4 waves, 4x4 frags 16x16x32, BK=32, 3-term split.
struct PArgs {
  const u32* Xp;     // [M][Kp] packed
  const ush* Wh;     // [256][Kp]
  const ush* Wlo;    // [256][Kp]
  const float* bias; // [256]
  const float* emb;  // [256]
  u32* out;          // h_pk + rowbase*kH
  int M, Kp;
};

__global__ __launch_bounds__(256) void k_pmg(PArgs g) {
  __shared__ u32 Apk[64 * 32];   // 8 KB
  __shared__ ush Wht[256 * 32];  // 16 KB
  __shared__ ush Wlt[256 * 32];  // 16 KB

  const int tid = threadIdx.x;
  const int wv = tid >> 6;
  const int l = tid & 63;
  const int fr = l & 15, fk = l >> 4;
  const int r0 = blockIdx.x * 64;

  const int ac0 = (((fk * 2) ^ (fr & 7)) * 4);
  const int ac1 = (((fk * 2 + 1) ^ (fr & 7)) * 4);
  const int wc8 = ((fk ^ (fr & 3)) * 8);

  const int arow = tid >> 3, ach = tid & 7;
  const int wrow = tid >> 2, wch = tid & 3;
  const int ar0g = (r0 + arow < g.M) ? (r0 + arow) : (g.M - 1);
  const int ar1g = (r0 + arow + 32 < g.M) ? (r0 + arow + 32) : (g.M - 1);
  const int aswz = (ach ^ (arow & 7)) * 4;
  const int wswz = (wch ^ (wrow & 3)) * 8;

  f32x4 acc[4][4];
#pragma unroll
  for (int m = 0; m < 4; ++m)
#pragma unroll
    for (int n = 0; n < 4; ++n) acc[m][n] = (f32x4)(0.f);

  const u32* a0 = g.Xp + (size_t)ar0g * g.Kp + aswz;
  const u32* a1 = g.Xp + (size_t)ar1g * g.Kp + aswz;
  const ush* wh = g.Wh + (size_t)wrow * g.Kp + wswz;
  const ush* wl = g.Wlo + (size_t)wrow * g.Kp + wswz;

#pragma unroll 1
  for (int kc = 0; kc < g.Kp; kc += 32) {
    __syncthreads();
    gload16(a0 + kc, Apk + tid * 4);
    gload16(a1 + kc, Apk + (tid + 256) * 4);
#pragma unroll
    for (int i = 0; i < 4; ++i) {
      gload16(wh + (size_t)i * 64 * g.Kp + kc, Wht + (tid + i * 256) * 8);
      gload16(wl + (size_t)i * 64 * g.Kp + kc, Wlt + (tid + i * 256) * 8);
    }
    __syncthreads();

    short8 ah[4], al[4], whf[4], wlf[4];
#pragma unroll
    for (int m = 0; m < 4; ++m) {
      const uint4 x = *(const uint4*)(Apk + (m * 16 + fr) * 32 + ac0);
      const uint4 y = *(const uint4*)(Apk + (m * 16 + fr) * 32 + ac1);
      unpk8(x, y, ah[m], al[m]);
    }
#pragma unroll
    for (int n = 0; n < 4; ++n) {
      whf[n] = *(const short8*)(Wht + (wv * 64 + n * 16 + fr) * 32 + wc8);
      wlf[n] = *(const short8*)(Wlt + (wv * 64 + n * 16 + fr) * 32 + wc8);
    }
#pragma unroll
    for (int m = 0; m < 4; ++m)
#pragma unroll
      for (int n = 0; n < 4; ++n) {
        acc[m][n] = __builtin_amdgcn_mfma_f32_16x16x32_bf16(ah[m], whf[n],
                                                            acc[m][n], 0, 0, 0);
        acc[m][n] = __builtin_amdgcn_mfma_f32_16x16x32_bf16(ah[m], wlf[n],
                                                            acc[m][n], 0, 0, 0);
        acc[m][n] = __builtin_amdgcn_mfma_f32_16x16x32_bf16(al[m], whf[n],
                                                            acc[m][n], 0, 0, 0);
      }
  }

  float bn[4];
#pragma unroll
  for (int n = 0; n < 4; ++n) {
    const int col = wv * 64 + n * 16 + fr;
    bn[n] = g.bias[col] + g.emb[col];
  }
#pragma unroll
  for (int m = 0; m < 4; ++m)
#pragma unroll
    for (int j = 0; j < 4; ++j) {
      const int ri = r0 + m * 16 + fk * 4 + j;
      if (ri < g.M) {
        u32* op = g.out + (size_t)ri * kH + wv * 64 + fr;
#pragma unroll
        for (int n = 0; n < 4; ++n) op[n * 16] = pk(acc[m][n][j] + bn[n]);
      }
    }
}

// ---------------- CSR build ----------------
__global__ __launch_bounds__(256) void k_scan1(const int* __restrict__ cnt,
                                               int* __restrict__ bsum) {
  __shared__ int s[256];
  int b = blockIdx.x, t = threadIdx.x;
  int i = b * 256 + t;
  s[t] = (i < kN) ? cnt[i] : 0;
  __syncthreads();
  for (int off = 128; off; off >>= 1) {
    if (t < off) s[t] += s[t + off];
    __syncthreads();
  }
  if (t == 0) bsum[b] = s[0];
}

__global__ __launch_bounds__(512) void k_scan2(const int* __restrict__ bsum,
                                               int* __restrict__ bscan) {
  __shared__ int s[512];
  int t = threadIdx.x;
  s[t] = (t < NBLK) ? bsum[t] : 0;
  __syncthreads();
  for (int off = 1; off < 512; off <<= 1) {
    int v = (t >= off) ? s[t - off] : 0;
    __syncthreads();
    s[t] += v;
    __syncthreads();
  }
  if (t < NBLK) bscan[t] = s[t];
}

__global__ __launch_bounds__(256) void k_scan3(const int* __restrict__ cnt,
                                               const int* __restrict__ bscan,
                                               int* __restrict__ rowptr,
                                               int* __restrict__ cursor,
                                               float* __restrict__ inv) {
  __shared__ int s[256];
  int b = blockIdx.x, t = threadIdx.x;
  int i = b * 256 + t;
  int v = (i < kN) ? cnt[i] : 0;
  s[t] = v;
  __syncthreads();
  for (int off = 1; off < 256; off <<= 1) {
    int u = (t >= off) ? s[t - off] : 0;
    __syncthreads();
    s[t] += u;
    __syncthreads();
  }
  int incl = s[t];
  int base = (b > 0) ? bscan[b - 1] : 0;
  int excl = base + incl - v;
  if (i < kN) {
    rowptr[i] = excl;
    cursor[i] = excl;
    inv[i] = 1.f / (float)(v > 1 ? v : 1);
    if (i == kN - 1) rowptr[kN] = excl + v;
  }
}

__global__ __launch_bounds__(256) void k_fill(const int* __restrict__ src_g,
                                              const int* __restrict__ dst_g,
                                              int* __restrict__ cursor,
                                              int* __restrict__ csr_src) {
  int e = blockIdx.x * 256 + threadIdx.x;
  if (e >= kE) return;
  int d = dst_g[e];
  int slot = atomicAdd(&cursor[d], 1);
  csr_src[slot] = src_g[e];
}

// ---------------- pull-mode mean aggregation (packed u32) ----------------
__global__ __launch_bounds__(256) void k_agg(const u32* __restrict__ hpk,
                                             const int* __restrict__ rowptr,
                                             const int* __restrict__ csr_src,
                                             const float* __restrict__ inv,
                                             u32* __restrict__ apk) {
  const int wave = threadIdx.x >> 6, lane = threadIdx.x & 63;
  const int node = blockIdx.x * 4 + wave;
  if (node >= kN) return;
  const int jb = rowptr[node], je = rowptr[node + 1];
  float a0 = 0.f, a1 = 0.f, a2 = 0.f, a3 = 0.f;
  const int coff = lane * 4;  // u32 col offset (16B/lane)

  int j = jb;
  while (j < je) {
    const int batch = min(je - j, 64);
    const int myi = (lane < batch) ? csr_src[j + lane] : 0;
    int t = 0;
    for (; t + 4 <= batch; t += 4) {
      const int s0 = __shfl(myi, t);
      const int s1 = __shfl(myi, t + 1);
      const int s2 = __shfl(myi, t + 2);
      const int s3 = __shfl(myi, t + 3);
      const uint4 v0 = *(const uint4*)(hpk + (size_t)s0 * kH + coff);
      const uint4 v1 = *(const uint4*)(hpk + (size_t)s1 * kH + coff);
      const uint4 v2 = *(const uint4*)(hpk + (size_t)s2 * kH + coff);
      const uint4 v3 = *(const uint4*)(hpk + (size_t)s3 * kH + coff);
      a0 += upk(v0.x) + upk(v1.x) + upk(v2.x) + upk(v3.x);
      a1 += upk(v0.y) + upk(v1.y) + upk(v2.y) + upk(v3.y);
      a2 += upk(v0.z) + upk(v1.z) + upk(v2.z) + upk(v3.z);
      a3 += upk(v0.w) + upk(v1.w) + upk(v2.w) + upk(v3.w);
    }
    for (; t < batch; ++t) {
      const int s0 = __shfl(myi, t);
      const uint4 v0 = *(const uint4*)(hpk + (size_t)s0 * kH + coff);
      a0 += upk(v0.x);
      a1 += upk(v0.y);
      a2 += upk(v0.z);
      a3 += upk(v0.w);
    }
    j += batch;
  }
  const float ic = inv[node];
  uint4 o;
  o.x = pk(a0 * ic);
  o.y = pk(a1 * ic);
  o.z = pk(a2 * ic);
  o.w = pk(a3 * ic);
  *(uint4*)(apk + (size_t)node * kH + coff) = o;
}

// ---------------- MFMA GEMM: packed-A, hi/lo-W, fused 3-term split ----------
struct GArgs {
  const u32* A[2];
  const ush* Wh[2];
  const ush* Wl[2];
  const float* bias;
  const float* lng;
  const float* lnb;
  const u32* rpk;
  float* outf;
  u32* opk;
  int M, npass, ostride;
};

template <bool LN>
__global__ __launch_bounds__(256) void k_mg(GArgs g) {
  __shared__ u32 Apk[64 * 32];   // 8 KB
  __shared__ ush Wht[256 * 32];  // 16 KB
  __shared__ ush Wlt[256 * 32];  // 16 KB
  __shared__ float redS[4][64];
  __shared__ float redQ[4][64];

  const int tid = threadIdx.x;
  const int wv = tid >> 6;
  const int l = tid & 63;
  const int fr = l & 15, fk = l >> 4;
  const int r0 = blockIdx.x * 64;
  const int cb = blockIdx.y << 8;

  const int ac0 = (((fk * 2) ^ (fr & 7)) * 4);
  const int ac1 = (((fk * 2 + 1) ^ (fr & 7)) * 4);
  const int wc8 = ((fk ^ (fr & 3)) * 8);

  const int arow = tid >> 3;
  const int ach = tid & 7;
  const int wrow = tid >> 2;
  const int wch = tid & 3;
  const int ar0g = (r0 + arow < g.M) ? (r0 + arow) : (g.M - 1);
  const int ar1g = (r0 + arow + 32 < g.M) ? (r0 + arow + 32) : (g.M - 1);
  const int aswz = (ach ^ (arow & 7)) * 4;
  const int wswz = (wch ^ (wrow & 3)) * 8;

  f32x4 acc[4][4];
#pragma unroll
  for (int m = 0; m < 4; ++m)
#pragma unroll
    for (int n = 0; n < 4; ++n) acc[m][n] = (f32x4)(0.f);

#pragma unroll 1
  for (int p = 0; p < g.npass; ++p) {
    const u32* a0 = g.A[p] + (size_t)ar0g * kH + aswz;
    const u32* a1 = g.A[p] + (size_t)ar1g * kH + aswz;
    const ush* wh = g.Wh[p] + (size_t)(cb + wrow) * kH + wswz;
    const ush* wl = g.Wl[p] + (size_t)(cb + wrow) * kH + wswz;
#pragma unroll 1
    for (int kc = 0; kc < kH; kc += 32) {
      __syncthreads();
      gload16(a0 + kc, Apk + tid * 4);
      gload16(a1 + kc, Apk + (tid + 256) * 4);
#pragma unroll
      for (int i = 0; i < 4; ++i) {
        gload16(wh + (size_t)i * 64 * kH + kc, Wht + (tid + i * 256) * 8);
        gload16(wl + (size_t)i * 64 * kH + kc, Wlt + (tid + i * 256) * 8);
      }
      __syncthreads();

      short8 ah[4], al[4], whf[4], wlf[4];
#pragma unroll
      for (int m = 0; m < 4; ++m) {
        const uint4 x = *(const uint4*)(Apk + (m * 16 + fr) * 32 + ac0);
        const uint4 y = *(const uint4*)(Apk + (m * 16 + fr) * 32 + ac1);
        unpk8(x, y, ah[m], al[m]);
      }
#pragma unroll
      for (int n = 0; n < 4; ++n) {
        whf[n] = *(const short8*)(Wht + (wv * 64 + n * 16 + fr) * 32 + wc8);
        wlf[n] = *(const short8*)(Wlt + (wv * 64 + n * 16 + fr) * 32 + wc8);
      }
#pragma unroll
      for (int m = 0; m < 4; ++m)
#pragma unroll
        for (int n = 0; n < 4; ++n) {
          acc[m][n] = __builtin_amdgcn_mfma_f32_16x16x32_bf16(ah[m], whf[n],
                                                              acc[m][n], 0, 0, 0);
          acc[m][n] = __builtin_amdgcn_mfma_f32_16x16x32_bf16(ah[m], wlf[n],
                                                              acc[m][n], 0, 0, 0);
          acc[m][n] = __builtin_amdgcn_mfma_f32_16x16x32_bf16(al[m], whf[n],
                                                              acc[m][n], 0, 0, 0);
        }
    }
  }

  float bn[4];
#pragma unroll
  for (int n = 0; n < 4; ++n) bn[n] = g.bias[cb + wv * 64 + n * 16 + fr];
#pragma unroll
  for (int m = 0; m < 4; ++m)
#pragma unroll
    for (int n = 0; n < 4; ++n)
#pragma unroll
      for (int j = 0; j < 4; ++j) acc[m][n][j] += bn[n];

  if (LN) {
#pragma unroll
    for (int m = 0; m < 4; ++m)
#pragma unroll
      for (int j = 0; j < 4; ++j) {
        float s = acc[m][0][j] + acc[m][1][j] + acc[m][2][j] + acc[m][3][j];
        float q = acc[m][0][j] * acc[m][0][j] + acc[m][1][j] * acc[m][1][j] +
                  acc[m][2][j] * acc[m][2][j] + acc[m][3][j] * acc[m][3][j];
#pragma unroll
        for (int d = 1; d < 16; d <<= 1) {
          s += __shfl_xor(s, d);
          q += __shfl_xor(q, d);
        }
        if (fr == 0) {
          redS[wv][m * 16 + fk * 4 + j] = s;
          redQ[wv][m * 16 + fk * 4 + j] = q;
        }
      }
    __syncthreads();
    float gg[4], eb[4];
#pragma unroll
    for (int n = 0; n < 4; ++n) {
      gg[n] = g.lng[wv * 64 + n * 16 + fr];
      eb[n] = g.lnb[wv * 64 + n * 16 + fr];
    }
#pragma unroll
    for (int m = 0; m < 4; ++m)
#pragma unroll
      for (int j = 0; j < 4; ++j) {
        const int rt = m * 16 + fk * 4 + j;
        const float S = redS[0][rt] + redS[1][rt] + redS[2][rt] + redS[3][rt];
        const float Q = redQ[0][rt] + redQ[1][rt] + redQ[2][rt] + redQ[3][rt];
        const float mu = S * (1.f / 256.f);
        float var = Q * (1.f / 256.f) - mu * mu;
        var = var > 0.f ? var : 0.f;
        const float rstd = rsqrtf(var + LN_EPS);
        const int ri = r0 + rt;
        if (ri < g.M) {
          const size_t base = (size_t)ri * kH + wv * 64 + fr;
#pragma unroll
          for (int n = 0; n < 4; ++n) {
            const size_t ix = base + n * 16;
            const float res = upk(g.rpk[ix]);
            const float y = (acc[m][n][j] - mu) * rstd * gg[n] + eb[n] + res;
            g.opk[ix] = pk(y);
          }
        }
      }
  } else {
#pragma unroll
    for (int m = 0; m < 4; ++m)
#pragma unroll
      for (int j = 0; j < 4; ++j) {
        const int ri = r0 + m * 16 + fk * 4 + j;
        if (ri < g.M) {
          float* op = g.outf + (size_t)ri * g.ostride + cb + wv * 64 + fr;
#pragma unroll
          for (int n = 0; n < 4; ++n) op[n * 16] = acc[m][n][j];
        }
      }
  }
}

// ---------------- weight hi/lo split (no pad; K=256 weights) ----------------
__global__ __launch_bounds__(256) void k_split(const float* __restrict__ s,
                                               ush* __restrict__ hi,
                                               ush* __restrict__ lo, int n) {
  int i = blockIdx.x * 256 + threadIdx.x;
  if (i >= n) return;
  float v = s[i];
  ush h = f2b(v);
  hi[i] = h;
  lo[i] = f2b(v - b2f(h));
}

// ---------------- host launch ----------------
extern "C" void kernel_launch(void* const* d_in, const int* in_sizes, int n_in,
                              void* d_out, int out_size, void* d_ws, size_t ws_size,
                              hipStream_t stream) {
  (void)in_sizes; (void)n_in; (void)out_size; (void)ws_size;
  const float* x_occ    = (const float*)d_in[0];
  const float* x_chord  = (const float*)d_in[1];
  const float* x_sec    = (const float*)d_in[2];
  const float* x_note   = (const float*)d_in[3];
  const float* x_sd     = (const float*)d_in[4];
  const int* ei[10];
  for (int i = 0; i < 10; ++i) ei[i] = (const int*)d_in[5 + i];
  const float* W_occ    = (const float*)d_in[15];
  const float* b_occ    = (const float*)d_in[16];
  const float* W_chord  = (const float*)d_in[17];
  const float* b_chord  = (const float*)d_in[18];
  const float* W_sec    = (const float*)d_in[19];
  const float* b_sec    = (const float*)d_in[20];
  const float* W_note   = (const float*)d_in[21];
  const float* b_note   = (const float*)d_in[22];
  const float* W_sd     = (const float*)d_in[23];
  const float* b_sd     = (const float*)d_in[24];
  const float* type_emb = (const float*)d_in[25];
  const float* Wl       = (const float*)d_in[26];
  const float* bl       = (const float*)d_in[27];
  const float* Wr       = (const float*)d_in[28];
  const float* ln_g     = (const float*)d_in[29];
  const float* ln_b     = (const float*)d_in[30];
  const float* Wc       = (const float*)d_in[31];
  const float* bc       = (const float*)d_in[32];

  char* base = (char*)d_ws;
  u32* h_pk   = (u32*)(base);                  // 108,083,200 B
  char* R = base + 108083200u;                 // agg_pk region (108 MB)
  u32* agg_pk = (u32*)R;
  char* wb = base + 216166400u;
  ush* Wl_hi = (ush*)(wb);
  ush* Wl_lo = (ush*)(wb + 393216u);
  ush* Wr_hi = (ush*)(wb + 786432u);
  ush* Wr_lo = (ush*)(wb + 1179648u);
  ush* Wc_hi = (ush*)(wb + 1572864u);
  ush* Wc_lo = (ush*)(wb + 2097152u);
  // padded proj weights [256][Kp] hi/lo
  ush* Wo_hi = (ush*)(wb + 2621440u);          // Kp=96: 49,152 B
  ush* Wo_lo = (ush*)(wb + 2670592u);
  ush* Wch_hi = (ush*)(wb + 2719744u);         // Kp=32: 16,384 B
  ush* Wch_lo = (ush*)(wb + 2736128u);
  ush* Wse_hi = (ush*)(wb + 2752512u);
  ush* Wse_lo = (ush*)(wb + 2768896u);
  ush* Wnt_hi = (ush*)(wb + 2785280u);
  ush* Wnt_lo = (ush*)(wb + 2801664u);
  ush* Wsd_hi = (ush*)(wb + 2818048u);
  ush* Wsd_lo = (ush*)(wb + 2834432u);
  int* ip = (int*)(wb + 2850816u);
  int* csr_src = ip;
  int* cnt     = ip + 605000;
  int* rowptr  = ip + 710550;
  int* cursor  = ip + 816101;
  float* inv   = (float*)(ip + 921651);
  int* bsum    = ip + 1027201;
  int* bscan   = ip + 1027614;
  // transient aliases inside agg_pk region (dead before first k_agg):
  float* cpo  = (float*)(R);                   // 10,240,000 B
  int* winner = (int*)(R + 10240000u);         // 320,000 B
  int* src_g  = (int*)(R + 10560000u);         // 2,420,000 B
  int* dst_g  = (int*)(R + 12980000u);         // 2,420,000 B
  u32* Xp_occ = (u32*)(R + 16000000u);         // 30,720,000 B
  u32* Xp_ch  = (u32*)(R + 46720000u);         // 2,560,000 B
  u32* Xp_se  = (u32*)(R + 49280000u);         // 640,000 B
  u32* Xp_nt  = (u32*)(R + 49920000u);         // 64,000 B
  u32* Xp_sd  = (u32*)(R + 49984000u);         // 6,400 B

  hipMemsetAsync(winner, 0xFF, kNo * 4, stream);
  hipMemsetAsync(cpo, 0, (size_t)kNo * 32 * 4, stream);
  hipMemsetAsync(cnt, 0, kN * 4, stream);

  // layer + classifier weight splits
  k_split<<<768, 256, 0, stream>>>(Wl, Wl_hi, Wl_lo, 3 * kH * kH);
  k_split<<<768, 256, 0, stream>>>(Wr, Wr_hi, Wr_lo, 3 * kH * kH);
  k_split<<<1024, 256, 0, stream>>>(Wc, Wc_hi, Wc_lo, kC * kH);

  // proj weight split + pad
  k_wsplit<<<(256 * 96 + 255) / 256, 256, 0, stream>>>(W_occ, 96, 96, Wo_hi, Wo_lo);
  k_wsplit<<<32, 256, 0, stream>>>(W_chord, 32, 32, Wch_hi, Wch_lo);
  k_wsplit<<<32, 256, 0, stream>>>(W_sec, 16, 32, Wse_hi, Wse_lo);
  k_wsplit<<<32, 256, 0, stream>>>(W_note, 16, 32, Wnt_hi, Wnt_lo);
  k_wsplit<<<32, 256, 0, stream>>>(W_sd, 8, 32, Wsd_hi, Wsd_lo);

  // chord -> occ feature scatter (numpy last-writer-wins)
  k_winner<<<(kNo + 255) / 256, 256, 0, stream>>>(ei[2], winner);
  k_scat<<<(kNo * 8) / 256, 256, 0, stream>>>(ei[2], winner, x_chord, cpo);

  // pack inputs (occ after cpo ready)
  k_pack2<<<(kNo * 96 + 255) / 256, 256, 0, stream>>>(x_occ, 64, cpo, 32, 96, Xp_occ, kNo);
  k_pack2<<<(kNc * 32 + 255) / 256, 256, 0, stream>>>(x_chord, 32, nullptr, 0, 32, Xp_ch, kNc);
  k_pack2<<<(kNs * 32 + 255) / 256, 256, 0, stream>>>(x_sec, 16, nullptr, 0, 32, Xp_se, kNs);
  k_pack2<<<(kNn * 32 + 255) / 256, 256, 0, stream>>>(x_note, 16, nullptr, 0, 32, Xp_nt, kNn);
  k_pack2<<<(kNd * 32 + 255) / 256, 256, 0, stream>>>(x_sd, 8, nullptr, 0, 32, Xp_sd, kNd);

  // MFMA projections -> h_pk
  {
    PArgs p{};
    p.Xp = Xp_occ; p.Wh = Wo_hi; p.Wlo = Wo_lo; p.bias = b_occ;
    p.emb = type_emb + 0 * kH; p.out = h_pk; p.M = kNo; p.Kp = 96;
    k_pmg<<<(kNo + 63) / 64, 256, 0, stream>>>(p);
    p.Xp = Xp_ch; p.Wh = Wch_hi; p.Wlo = Wch_lo; p.bias = b_chord;
    p.emb = type_emb + 1 * kH; p.out = h_pk + (size_t)kNo * kH; p.M = kNc; p.Kp = 32;
    k_pmg<<<(kNc + 63) / 64, 256, 0, stream>>>(p);
    p.Xp = Xp_se; p.Wh = Wse_hi; p.Wlo = Wse_lo; p.bias = b_sec;
    p.emb = type_emb + 2 * kH; p.out = h_pk + (size_t)100000 * kH; p.M = kNs; p.Kp = 32;
    k_pmg<<<(kNs + 63) / 64, 256, 0, stream>>>(p);
    p.Xp = Xp_nt; p.Wh = Wnt_hi; p.Wlo = Wnt_lo; p.bias = b_note;
    p.emb = type_emb + 3 * kH; p.out = h_pk + (size_t)105000 * kH; p.M = kNn; p.Kp = 32;
    k_pmg<<<(kNn + 63) / 64, 256, 0, stream>>>(p);
    p.Xp = Xp_sd; p.Wh = Wsd_hi; p.Wlo = Wsd_lo; p.bias = b_sd;
    p.emb = type_emb + 4 * kH; p.out = h_pk + (size_t)105500 * kH; p.M = kNd; p.Kp = 32;
    k_pmg<<<(kNd + 63) / 64, 256, 0, stream>>>(p);
  }

  // homogeneous edge list + CSR
  EdgeTab tab;
  const int ns_[10]  = {80000, 80000, 80000, 80000, 80000, 5000, 80000, 80000, 20000, 20000};
  const int sos_[10] = {0, 0, 80000, 0, 100000, 100000, 80000, 105000, 80000, 105500};
  const int dos_[10] = {0, 80000, 0, 100000, 0, 100000, 105000, 80000, 105500, 80000};
  int cum = 0;
  for (int i = 0; i < 10; ++i) {
    tab.p[i] = ei[i]; tab.n[i] = ns_[i]; tab.so[i] = sos_[i]; tab.dofs[i] = dos_[i];
    tab.cum[i] = cum; cum += ns_[i];
  }
  tab.cum[10] = cum;

  k_edges<<<(kE + 255) / 256, 256, 0, stream>>>(tab, src_g, dst_g, cnt);
  k_scan1<<<NBLK, 256, 0, stream>>>(cnt, bsum);
  k_scan2<<<1, 512, 0, stream>>>(bsum, bscan);
  k_scan3<<<NBLK, 256, 0, stream>>>(cnt, bscan, rowptr, cursor, inv);
  k_fill<<<(kE + 255) / 256, 256, 0, stream>>>(src_g, dst_g, cursor, csr_src);

  // 3 SAGE layers
  for (int l = 0; l < 3; ++l) {
    k_agg<<<(kN + 3) / 4, 256, 0, stream>>>(h_pk, rowptr, csr_src, inv, agg_pk);
    GArgs a{};
    const size_t off = (size_t)l * kH * kH;
    a.A[0] = agg_pk;      a.A[1] = h_pk;
    a.Wh[0] = Wl_hi + off; a.Wh[1] = Wr_hi + off;
    a.Wl[0] = Wl_lo + off; a.Wl[1] = Wr_lo + off;
    a.bias = bl + l * kH;
    a.lng = ln_g + l * kH;
    a.lnb = ln_b + l * kH;
    a.rpk = h_pk;
    a.outf = nullptr;
    a.opk = h_pk;
    a.M = kN; a.npass = 2; a.ostride = kH;
    k_mg<true><<<dim3((kN + 63) / 64, 1), 256, 0, stream>>>(a);
  }

  // classifier head over occ nodes
  GArgs c{};
  c.A[0] = h_pk;
  c.Wh[0] = Wc_hi;
  c.Wl[0] = Wc_lo;
  c.bias = bc;
  c.rpk = nullptr;
  c.outf = (float*)d_out;
  c.opk = nullptr;
  c.M = kNo; c.npass = 1; c.ostride = kC;
  k_mg<false><<<dim3(kNo / 64, 4), 256, 0, stream>>>(c);
}